// Round 7
// baseline (58.501 us; speedup 1.0000x reference)
//
#include <hip/hip_runtime.h>

#define NW 12
#define DIM 4096
#define NL 4
#define NGATE 48
#define NOUT 4
#define TPB 512
#define TB 9              // thread bits
#define KB 3              // register bits (8 amps/thread)
#define NGRP 16           // 16 groups of 3 gates
#define APTH 8            // amps per thread

typedef float f32x2 __attribute__((ext_vector_type(2)));

// ======================= constexpr GF(2) machinery =======================
// State in registers: phys y = k*512 + t (k = 3 reg bits, t = 9 thread bits).
// Per group g (3 gates), basis B_g (storage = B_g(phys)):
//   B_g(e_{9+i}) = m_i          (gate pair masks -> reg bits)
//   cols(B_g) ⊥ rm_i except 9+i (gate role == reg bit, no selects)
// Exchange g-1 -> g: value with old-frame coord y stored at amp[W_g(y)],
// W_g a bijection whose 4 nibble rows are rank-4 on BOTH S1 = span(lane
// bits e_0..e_5) and S2 = span(u_0..u_5) -> write and read lane->bank-pair
// maps are exactly 4-to-1 (b64 floor). Constructive two-subspace avoidance.

constexpr int pcnt(unsigned x){ return __builtin_popcount(x); }
constexpr int msbp(unsigned x){ return x ? 31-__builtin_clz(x) : -1; }
constexpr unsigned ring_fwd(unsigned x,int r){
  for(int w=0;w<NW;++w){ int c=NW-1-w,t=NW-1-((w+r)%NW); x^=((x>>c)&1u)<<t; } return x;
}
constexpr unsigned ring_rev(unsigned x,int r){
  for(int w=NW-1;w>=0;--w){ int c=NW-1-w,t=NW-1-((w+r)%NW); x^=((x>>c)&1u)<<t; } return x;
}

struct Mat { unsigned col[12]; };
constexpr unsigned apply_cols(const Mat&M, unsigned v){
  unsigned r=0; for(int j=0;j<12;++j) if((v>>j)&1u) r^=M.col[j]; return r;
}
constexpr unsigned apply_rows(const unsigned* rows, unsigned v){
  unsigned r=0; for(int i=0;i<12;++i) r|=(unsigned)(pcnt(rows[i]&v)&1)<<i; return r;
}
constexpr bool invert_rows(const Mat&M, unsigned* ri_out){
  unsigned rb[12]={}, ri[12]={};
  for(int i=0;i<12;++i){ unsigned r=0; for(int j=0;j<12;++j) r|=((M.col[j]>>i)&1u)<<j; rb[i]=r; ri[i]=1u<<i; }
  for(int c=0;c<12;++c){
    int piv=-1; for(int r=c;r<12;++r) if((rb[r]>>c)&1u){piv=r;break;}
    if(piv<0) return false;
    unsigned t=rb[c]; rb[c]=rb[piv]; rb[piv]=t; t=ri[c]; ri[c]=ri[piv]; ri[piv]=t;
    for(int r=0;r<12;++r) if(r!=c&&((rb[r]>>c)&1u)){ rb[r]^=rb[c]; ri[r]^=ri[c]; }
  }
  for(int i=0;i<12;++i) ri_out[i]=ri[i];
  return true;
}
constexpr int nullspaceN(const unsigned* A0, int n, unsigned* out){
  unsigned A[4]={}; for(int i=0;i<n;++i) A[i]=A0[i];
  int rank=0; int pivc[4]={-1,-1,-1,-1};
  for(int c=0;c<12&&rank<n;++c){
    int piv=-1; for(int r=rank;r<n;++r) if((A[r]>>c)&1u){piv=r;break;}
    if(piv<0) continue;
    unsigned tt=A[rank];A[rank]=A[piv];A[piv]=tt;
    for(int r=0;r<n;++r) if(r!=rank&&((A[r]>>c)&1u)) A[r]^=A[rank];
    pivc[rank]=c; ++rank;
  }
  if(rank!=n) return -1;
  bool ispiv[12]={};
  for(int r=0;r<n;++r) ispiv[pivc[r]]=true;
  int cnt=0;
  for(int f=0;f<12;++f) if(!ispiv[f]){
    unsigned v=1u<<f;
    for(int r=0;r<n;++r) if((A[r]>>f)&1u) v|=1u<<pivc[r];
    out[cnt++]=v;
  }
  return cnt;
}
struct Ech { unsigned r[12]; int lead[12]; int n; };
constexpr unsigned ech_red(const Ech&e, unsigned v){
  int mv=msbp(v);
  for(int i=0;i<e.n&&v;++i) if(e.lead[i]==mv){ v^=e.r[i]; mv=msbp(v); }
  return v;
}
constexpr void ech_add(Ech&e, unsigned v){   // pre-reduced, nonzero
  int l=msbp(v); int pos=e.n;
  while(pos>0&&e.lead[pos-1]<l){ e.r[pos]=e.r[pos-1]; e.lead[pos]=e.lead[pos-1]; --pos; }
  e.r[pos]=v; e.lead[pos]=l; e.n+=1;
}

struct Plan {
  unsigned SCOL0[TB];       // B_0 thread-bit columns
  unsigned SK8_0[8];        // B_0 reg-bit XOR combos
  unsigned WTC[NGRP][TB];   // exchange g: write cols  W(e_j)
  unsigned WK8[NGRP][8];    // exchange g: write k-combos XOR W(e_{9+i})
  unsigned RDC[NGRP][TB];   // exchange g: read cols   W(u_j)
  unsigned WRK8[NGRP][8];   // exchange g: read k-combos XOR W(rk_i)
  unsigned SRlow[NOUT], SRhigh[NOUT];
  unsigned TM;              // wires touched by B_0 reg cols
  bool ok;
};

constexpr Plan make_plan(){
  Plan P{}; P.ok=true;
  unsigned cols[12]={}, icols[12]={};
  for(int p=0;p<12;++p){ cols[p]=1u<<p; icols[p]=1u<<p; }
  unsigned M[NL][12]={}, RM[NL][12]={}, MR[NOUT]={};
  for(int l=0;l<NL;++l){
    for(int w=0;w<NW;++w){
      int p=NW-1-w;
      M[l][w]=icols[p];
      unsigned r=0; for(int j=0;j<12;++j) r|=((cols[j]>>p)&1u)<<j;
      RM[l][w]=r;
    }
    int rr=(l%(NW-1))+1;
    for(int j=0;j<12;++j) cols[j]=ring_fwd(cols[j],rr);
    unsigned nic[12]={};
    for(int p=0;p<12;++p){
      unsigned y=ring_rev(1u<<p,rr), v=0;
      for(int q=0;q<12;++q) if((y>>q)&1u) v^=icols[q];
      nic[p]=v;
    }
    for(int p=0;p<12;++p) icols[p]=nic[p];
  }
  for(int o=0;o<NOUT;++o){
    int p=NW-1-o; unsigned r=0;
    for(int j=0;j<12;++j) r|=((cols[j]>>p)&1u)<<j;
    MR[o]=r;
  }
  Mat Bprev{}; for(int j=0;j<12;++j) Bprev.col[j]=1u<<j;
  for(int g=0; g<NGRP; ++g){
    int l=g/4, j0=(g%4)*KB;
    unsigned mi[KB]={}, rmi[KB]={};
    for(int i=0;i<KB;++i){ mi[i]=M[l][j0+i]; rmi[i]=RM[l][j0+i]; }
    unsigned u[TB]={};
    if(nullspaceN(rmi,KB,u)!=TB){ P.ok=false; return P; }
    unsigned binv[12]={};
    if(!invert_rows(Bprev,binv)){ P.ok=false; return P; }
    for(int s=0;s<TB;++s) u[s]=apply_rows(binv,u[s]);    // prev-frame coords
    Mat Bg{};
    for(int j=0;j<TB;++j) Bg.col[j]=apply_cols(Bprev,u[j]);
    for(int i=0;i<KB;++i) Bg.col[TB+i]=mi[i];
    unsigned tinv[12]={};
    if(!invert_rows(Bg,tinv)){ P.ok=false; return P; }
    for(int i=0;i<KB;++i)
      for(int j=0;j<12;++j){
        int want=(j==TB+i)?1:0;
        if((pcnt(Bg.col[j]&rmi[i])&1)!=want){ P.ok=false; return P; }
      }
    if(g==0){
      for(int j=0;j<TB;++j) P.SCOL0[j]=Bg.col[j];
      unsigned tm=0;
      for(int k=0;k<8;++k){
        unsigned v=0; for(int i=0;i<KB;++i) if((k>>i)&1) v^=Bg.col[TB+i];
        P.SK8_0[k]=v; tm|=v;
      }
      P.TM=tm;
    } else {
      unsigned rk[KB]={};
      for(int i=0;i<KB;++i){
        rk[i]=apply_rows(binv,mi[i]);
        if(apply_cols(Bprev,rk[i])!=mi[i]){ P.ok=false; return P; }
      }
      // ---- constructive W: 4 rows rank-4 on pi1 (f&63) and pi2 (f vs u_j, j<6) ----
      unsigned row2[12]={};
      for(int bb=0;bb<12;++bb){
        unsigned r=0;
        for(int j=0;j<6;++j) r |= ((u[j]>>bb)&1u) << j;
        row2[bb]=r;
      }
      unsigned rows[12]={}; int nr=0;
      Ech P1{}; Ech P2{}; Ech ER{};
      for(int pick=0;pick<4;++pick){
        int b1=-1;
        for(int bb=0;bb<6;++bb){ if(ech_red(P1, 1u<<bb)){ b1=bb; break; } }
        int b2=-1;
        for(int bb=0;bb<12;++bb){ if(ech_red(P2, row2[bb])){ b2=bb; break; } }
        if(b1<0||b2<0){ P.ok=false; return P; }
        unsigned p2x=row2[b1];
        unsigned p1y=(b2<6)?(1u<<b2):0u;
        unsigned f=0, p1f=0, p2f=0;
        if(ech_red(P2,p2x))      { f=1u<<b1;            p1f=1u<<b1;          p2f=p2x; }
        else if(ech_red(P1,p1y)) { f=1u<<b2;            p1f=p1y;             p2f=row2[b2]; }
        else                     { f=(1u<<b1)^(1u<<b2); p1f=(1u<<b1)^p1y;    p2f=p2x^row2[b2]; }
        unsigned v1=ech_red(P1,p1f), v2=ech_red(P2,p2f);
        if(!v1||!v2){ P.ok=false; return P; }
        ech_add(P1,v1); ech_add(P2,v2);
        unsigned vr=ech_red(ER,f);
        if(!vr){ P.ok=false; return P; }
        ech_add(ER,vr);
        rows[nr++]=f;
      }
      for(int bb=0;bb<12 && nr<12;++bb){
        unsigned vr=ech_red(ER,1u<<bb); if(!vr) continue;
        ech_add(ER,vr); rows[nr++]=1u<<bb;
      }
      if(nr!=12){ P.ok=false; return P; }
      unsigned Wcol[12]={};
      for(int j=0;j<12;++j){
        unsigned v=0;
        for(int i=0;i<12;++i) v |= ((rows[i]>>j)&1u)<<i;
        Wcol[j]=v;
      }
      for(int j=0;j<TB;++j){
        P.WTC[g][j]=Wcol[j];
        unsigned v=0;
        for(int q=0;q<12;++q) if((u[j]>>q)&1u) v^=Wcol[q];
        P.RDC[g][j]=v;
      }
      for(int k=0;k<8;++k){
        unsigned wv=0, rv=0;
        for(int i=0;i<KB;++i) if((k>>i)&1){
          wv ^= Wcol[TB+i];
          unsigned v=0;
          for(int q=0;q<12;++q) if((rk[i]>>q)&1u) v^=Wcol[q];
          rv ^= v;
        }
        P.WK8[g][k]=wv; P.WRK8[g][k]=rv;
      }
    }
    Bprev=Bg;
  }
  for(int o=0;o<NOUT;++o){
    unsigned sr=0;
    for(int j=0;j<12;++j) sr|=(unsigned)(pcnt(Bprev.col[j]&MR[o])&1)<<j;
    P.SRlow[o]=sr&511u; P.SRhigh[o]=sr>>TB;
  }
  return P;
}

constexpr Plan PLC = make_plan();        // single constexpr evaluation
static_assert(PLC.ok, "basis/bank planning failed");
__device__ constexpr Plan PL = PLC;      // constant init (copy), no re-eval

// ======================= device helpers =======================

__device__ __forceinline__ void apply_group(f32x2* a, const float* gw_base, int g){
  #pragma unroll
  for(int i=0;i<KB;++i){
    const float* w = gw_base + (g*KB+i)*8;
    f32x2 c00={w[0],w[0]}, d00={-w[1],w[1]};
    f32x2 c01={w[2],w[2]}, d01={-w[3],w[3]};
    f32x2 c10={w[4],w[4]}, d10={-w[5],w[5]};
    f32x2 c11={w[6],w[6]}, d11={-w[7],w[7]};
    #pragma unroll
    for(int q=0;q<4;++q){
      const int k0=((q>>i)<<(i+1))|(q&((1<<i)-1));
      const int k1=k0|(1<<i);
      f32x2 a0=a[k0], a1=a[k1];
      f32x2 a0s=a0.yx, a1s=a1.yx;
      f32x2 n0 = c00*a0 + d00*a0s + c01*a1 + d01*a1s;
      f32x2 n1 = c10*a0 + d10*a0s + c11*a1 + d11*a1s;
      a[k0]=n0; a[k1]=n1;
    }
  }
}

__device__ __forceinline__ void gate_coeffs(const float* __restrict__ wts, int gi, float* o){
  const float* w = wts + gi*3;
  float st,ct;  sincosf(0.5f*w[1],&st,&ct);
  float sap,cap; sincosf(0.5f*(w[0]+w[2]),&sap,&cap);
  float sam,cam; sincosf(0.5f*(w[0]-w[2]),&sam,&cam);
  o[0]= cap*ct; o[1]=-sap*ct;
  o[2]=-cam*st; o[3]=-sam*st;
  o[4]= cam*st; o[5]=-sam*st;
  o[6]= cap*ct; o[7]= sap*ct;
}

__global__ void coeff_kernel(const float* __restrict__ wts, float* __restrict__ gws){
  int gi = threadIdx.x;
  if(gi >= NGATE) return;
  float o[8];
  gate_coeffs(wts, gi, o);
  #pragma unroll
  for(int j=0;j<8;++j) gws[gi*8+j]=o[j];
}

// ======================= main kernel =======================

template<bool USE_WS>
__global__ __launch_bounds__(TPB,8)
void vqc_kernel(const float* __restrict__ inp,   // (B,12)
                const float* __restrict__ wts,   // (4,12,3) fallback
                const float* __restrict__ gws,   // (48,8) precomputed
                float* __restrict__ out)         // (B,4)
{
  constexpr int SMEM_BYTES = DIM*8 + (USE_WS?0:NGATE*8*4);
  __shared__ __align__(16) char smem[SMEM_BYTES];
  f32x2* amp = (f32x2*)smem;
  float* cs  = (float*)smem;         // floats 0..11   (pre-amp phase)
  float* ss  = cs + NW;              // floats 12..23  (pre-amp phase)
  float* red = cs + 2*NW;            // floats 24..55  (post-amp phase)
  float* gtab = (float*)(smem + DIM*8);  // fallback only

  const int t = threadIdx.x;
  const int b = blockIdx.x;

  if(t < NW){
    float x = inp[b*NW+t];
    float s,c; sincosf(0.78539816339744830962f*x,&s,&c);
    cs[t]=c; ss[t]=s;
  }
  if(!USE_WS && t < NGATE){
    float o[8]; gate_coeffs(wts,t,o);
    #pragma unroll
    for(int j=0;j<8;++j) gtab[t*8+j]=o[j];
  }
  __syncthreads();

  const float* gw = USE_WS ? gws : (const float*)gtab;

  // product-state init in basis B_0 (reads cs/ss broadcast from LDS)
  unsigned sig_t=0;
  #pragma unroll
  for(int j=0;j<TB;++j) sig_t ^= ((t>>j)&1u)? PL.SCOL0[j] : 0u;
  float pbase=1.f;
  #pragma unroll
  for(int p=0;p<12;++p)
    if(!((PL.TM>>p)&1u))
      pbase *= ((sig_t>>p)&1u)? ss[11-p] : cs[11-p];
  f32x2 a[APTH];
  #pragma unroll
  for(int k=0;k<APTH;++k){
    float pk=pbase;
    #pragma unroll
    for(int p=0;p<12;++p)
      if((PL.TM>>p)&1u){
        unsigned bit = ((sig_t ^ PL.SK8_0[k])>>p)&1u;
        pk *= bit? ss[11-p] : cs[11-p];
      }
    a[k].x=pk; a[k].y=0.f;
  }

  apply_group(a, gw, 0);

  #pragma unroll 1
  for(int g=1; g<NGRP; ++g){
    unsigned wb=0, rb=0;
    #pragma unroll
    for(int j=0;j<TB;++j){
      wb ^= ((t>>j)&1u)? PL.WTC[g][j] : 0u;
      rb ^= ((t>>j)&1u)? PL.RDC[g][j] : 0u;
    }
    __syncthreads();                           // prior reads done
    #pragma unroll
    for(int k=0;k<APTH;++k) amp[wb ^ PL.WK8[g][k]] = a[k];   // rank-4 banks
    __syncthreads();
    #pragma unroll
    for(int k=0;k<APTH;++k) a[k] = amp[rb ^ PL.WRK8[g][k]];  // rank-4 banks
    apply_group(a, gw, g);
  }

  // expval(PauliZ) wires 0..3 from registers
  float acc[NOUT]={0.f,0.f,0.f,0.f};
  float sg[NOUT];
  #pragma unroll
  for(int o=0;o<NOUT;++o)
    sg[o] = (__popc((unsigned)t & PL.SRlow[o])&1)? -1.f : 1.f;
  #pragma unroll
  for(int k=0;k<APTH;++k){
    float pr = a[k].x*a[k].x + a[k].y*a[k].y;
    #pragma unroll
    for(int o=0;o<NOUT;++o){
      const bool kp = (pcnt((unsigned)k & PL.SRhigh[o])&1)!=0;  // compile-time
      float f = sg[o]*pr;
      acc[o] += kp ? -f : f;
    }
  }
  #pragma unroll
  for(int o=0;o<NOUT;++o)
    #pragma unroll
    for(int off=32; off>0; off>>=1)
      acc[o] += __shfl_down(acc[o], off);
  __syncthreads();                 // all amp reads done before red aliases it
  const int wv=t>>6, ln=t&63;
  if(ln==0){
    #pragma unroll
    for(int o=0;o<NOUT;++o) red[wv*NOUT+o]=acc[o];
  }
  __syncthreads();
  if(t<NOUT){
    float s = red[0*NOUT+t]+red[1*NOUT+t]+red[2*NOUT+t]+red[3*NOUT+t]
            + red[4*NOUT+t]+red[5*NOUT+t]+red[6*NOUT+t]+red[7*NOUT+t];
    out[b*NOUT+t] = s;
  }
}

// ======================= launch =======================

extern "C" void kernel_launch(void* const* d_in, const int* in_sizes, int n_in,
                              void* d_out, int out_size, void* d_ws, size_t ws_size,
                              hipStream_t stream) {
  const float* inp=(const float*)d_in[0];   // (1024,12) f32
  const float* wts=(const float*)d_in[1];   // (4,12,3) f32
  float* outp=(float*)d_out;                // (1024,4) f32
  const int B = in_sizes[0]/NW;
  if(ws_size >= (size_t)(NGATE*8*sizeof(float))){
    float* gws=(float*)d_ws;
    coeff_kernel<<<1,64,0,stream>>>(wts,gws);
    vqc_kernel<true><<<B,TPB,0,stream>>>(inp,wts,gws,outp);
  } else {
    vqc_kernel<false><<<B,TPB,0,stream>>>(inp,wts,nullptr,outp);
  }
}

// Round 8
// 53.677 us; speedup vs baseline: 1.0899x; 1.0899x over previous
//
#include <hip/hip_runtime.h>

#define NW 12
#define DIM 4096
#define NL 4
#define NGATE 48
#define NOUT 4
#define TPB 256

typedef float f32x2 __attribute__((ext_vector_type(2)));
typedef double cpair;   // 64-bit carrier for a packed [lo,hi] f32 coefficient pair

// packed complex FMA building blocks (CDNA4 VOP3P).
// D = S0*S1 (+D), elementwise on f32 pairs; _SW swaps the halves of the
// amplitude source via op_sel (low op takes hi half, high op takes lo half).
#define PK_MUL(d0, s0, s1)   asm("v_pk_mul_f32 %0, %1, %2"     : "=v"(d0) : "s"(s0), "v"(s1))
#define PK_FMA(d0, s0, s1)   asm("v_pk_fma_f32 %0, %1, %2, %0" : "+v"(d0) : "s"(s0), "v"(s1))
#define PK_FMA_SW(d0, s0, s1) asm("v_pk_fma_f32 %0, %1, %2, %0 op_sel:[0,1,0] op_sel_hi:[1,0,1]" : "+v"(d0) : "s"(s0), "v"(s1))

// ======================= constexpr GF(2) machinery =======================
// State in registers: phys y = k*256 + t (k = 4 reg bits, t = 8 thread bits).
// Per group g (4 gates), basis B_g (storage = B_g(phys)):
//   B_g(e_{8+i}) = m_i          (gate pair masks -> reg bits)
//   cols(B_g) ⊥ rm_i except 8+i (gate role == reg bit, no selects)
// Exchange g-1 -> g: value with old-frame coord y stored at amp[W_g(y)],
// W_g a bijection whose 4 nibble rows are rank-4 on BOTH S1 = span(lane
// bits) and S2 = span(u_j lane images) -> write and read lane->bank-pair
// maps are exactly 4-to-1 (b64 floor). Constructive two-subspace avoidance.

constexpr int pcnt(unsigned x){ return __builtin_popcount(x); }
constexpr int msbp(unsigned x){ return x ? 31-__builtin_clz(x) : -1; }
constexpr unsigned ring_fwd(unsigned x,int r){
  for(int w=0;w<NW;++w){ int c=NW-1-w,t=NW-1-((w+r)%NW); x^=((x>>c)&1u)<<t; } return x;
}
constexpr unsigned ring_rev(unsigned x,int r){
  for(int w=NW-1;w>=0;--w){ int c=NW-1-w,t=NW-1-((w+r)%NW); x^=((x>>c)&1u)<<t; } return x;
}

struct Mat { unsigned col[12]; };
constexpr unsigned apply_cols(const Mat&M, unsigned v){
  unsigned r=0; for(int j=0;j<12;++j) if((v>>j)&1u) r^=M.col[j]; return r;
}
constexpr unsigned apply_rows(const unsigned* rows, unsigned v){
  unsigned r=0; for(int i=0;i<12;++i) r|=(unsigned)(pcnt(rows[i]&v)&1)<<i; return r;
}
constexpr bool invert_rows(const Mat&M, unsigned* ri_out){
  unsigned rb[12]={}, ri[12]={};
  for(int i=0;i<12;++i){ unsigned r=0; for(int j=0;j<12;++j) r|=((M.col[j]>>i)&1u)<<j; rb[i]=r; ri[i]=1u<<i; }
  for(int c=0;c<12;++c){
    int piv=-1; for(int r=c;r<12;++r) if((rb[r]>>c)&1u){piv=r;break;}
    if(piv<0) return false;
    unsigned t=rb[c]; rb[c]=rb[piv]; rb[piv]=t; t=ri[c]; ri[c]=ri[piv]; ri[piv]=t;
    for(int r=0;r<12;++r) if(r!=c&&((rb[r]>>c)&1u)){ rb[r]^=rb[c]; ri[r]^=ri[c]; }
  }
  for(int i=0;i<12;++i) ri_out[i]=ri[i];
  return true;
}
constexpr int nullspace4(const unsigned* A0, unsigned* out){
  unsigned A[4]={}; for(int i=0;i<4;++i) A[i]=A0[i];
  int rank=0; int pivc[4]={-1,-1,-1,-1};
  for(int c=0;c<12&&rank<4;++c){
    int piv=-1; for(int r=rank;r<4;++r) if((A[r]>>c)&1u){piv=r;break;}
    if(piv<0) continue;
    unsigned t=A[rank];A[rank]=A[piv];A[piv]=t;
    for(int r=0;r<4;++r) if(r!=rank&&((A[r]>>c)&1u)) A[r]^=A[rank];
    pivc[rank]=c; ++rank;
  }
  if(rank!=4) return -1;
  bool ispiv[12]={};
  for(int r=0;r<4;++r) ispiv[pivc[r]]=true;
  int cnt=0;
  for(int f=0;f<12;++f) if(!ispiv[f]){
    unsigned v=1u<<f;
    for(int r=0;r<4;++r) if((A[r]>>f)&1u) v|=1u<<pivc[r];
    out[cnt++]=v;
  }
  return cnt;
}
struct Ech { unsigned r[12]; int lead[12]; int n; };
constexpr unsigned ech_red(const Ech&e, unsigned v){
  int mv=msbp(v);
  for(int i=0;i<e.n&&v;++i) if(e.lead[i]==mv){ v^=e.r[i]; mv=msbp(v); }
  return v;
}
constexpr void ech_add(Ech&e, unsigned v){   // pre-reduced, nonzero
  int l=msbp(v); int pos=e.n;
  while(pos>0&&e.lead[pos-1]<l){ e.r[pos]=e.r[pos-1]; e.lead[pos]=e.lead[pos-1]; --pos; }
  e.r[pos]=v; e.lead[pos]=l; e.n+=1;
}

struct Plan {
  unsigned SCOL0[8];      // B_0 thread-bit columns
  unsigned SK16_0[16];    // B_0 reg-bit XOR combos
  unsigned WTC[12][8];    // exchange g: write cols  W(e_j), j=t-bit
  unsigned WK16[12][16];  // exchange g: write k-combos XOR W(e_{8+i})
  unsigned RDC[12][8];    // exchange g: read cols   W(u_j)
  unsigned WRK16[12][16]; // exchange g: read k-combos XOR W(rk_i)
  unsigned SRlow[NOUT], SRhigh[NOUT];
  unsigned TM;            // wires touched by B_0 reg cols
  bool ok;
};

constexpr Plan make_plan(){
  Plan P{}; P.ok=true;
  unsigned cols[12]={}, icols[12]={};
  for(int p=0;p<12;++p){ cols[p]=1u<<p; icols[p]=1u<<p; }
  unsigned M[NL][12]={}, RM[NL][12]={}, MR[NOUT]={};
  for(int l=0;l<NL;++l){
    for(int w=0;w<NW;++w){
      int p=NW-1-w;
      M[l][w]=icols[p];
      unsigned r=0; for(int j=0;j<12;++j) r|=((cols[j]>>p)&1u)<<j;
      RM[l][w]=r;
    }
    int rr=(l%(NW-1))+1;
    for(int j=0;j<12;++j) cols[j]=ring_fwd(cols[j],rr);
    unsigned nic[12]={};
    for(int p=0;p<12;++p){
      unsigned y=ring_rev(1u<<p,rr), v=0;
      for(int q=0;q<12;++q) if((y>>q)&1u) v^=icols[q];
      nic[p]=v;
    }
    for(int p=0;p<12;++p) icols[p]=nic[p];
  }
  for(int o=0;o<NOUT;++o){
    int p=NW-1-o; unsigned r=0;
    for(int j=0;j<12;++j) r|=((cols[j]>>p)&1u)<<j;
    MR[o]=r;
  }
  Mat Bprev{}; for(int j=0;j<12;++j) Bprev.col[j]=1u<<j;
  for(int g=0; g<12; ++g){
    int l=g/3, j0=(g%3)*4;
    unsigned mi[4]={}, rmi[4]={};
    for(int i=0;i<4;++i){ mi[i]=M[l][j0+i]; rmi[i]=RM[l][j0+i]; }
    unsigned u[8]={};
    if(nullspace4(rmi,u)!=8){ P.ok=false; return P; }
    unsigned binv[12]={};
    if(!invert_rows(Bprev,binv)){ P.ok=false; return P; }
    for(int s=0;s<8;++s) u[s]=apply_rows(binv,u[s]);    // prev-frame coords
    Mat Bg{};
    for(int j=0;j<8;++j) Bg.col[j]=apply_cols(Bprev,u[j]);
    for(int i=0;i<4;++i) Bg.col[8+i]=mi[i];
    unsigned tinv[12]={};
    if(!invert_rows(Bg,tinv)){ P.ok=false; return P; }
    for(int i=0;i<4;++i)
      for(int j=0;j<12;++j){
        int want=(j==8+i)?1:0;
        if((pcnt(Bg.col[j]&rmi[i])&1)!=want){ P.ok=false; return P; }
      }
    if(g==0){
      for(int j=0;j<8;++j) P.SCOL0[j]=Bg.col[j];
      unsigned tm=0;
      for(int k=0;k<16;++k){
        unsigned v=0; for(int i=0;i<4;++i) if((k>>i)&1) v^=Bg.col[8+i];
        P.SK16_0[k]=v; tm|=v;
      }
      P.TM=tm;
    } else {
      unsigned rk[4]={};
      for(int i=0;i<4;++i){
        rk[i]=apply_rows(binv,mi[i]);
        if(apply_cols(Bprev,rk[i])!=mi[i]){ P.ok=false; return P; }
      }
      // ---- constructive W: 4 rows rank-4 on pi1 (f&63) and pi2 (f vs u_j, j<6) ----
      unsigned row2[12]={};
      for(int bb=0;bb<12;++bb){
        unsigned r=0;
        for(int j=0;j<6;++j) r |= ((u[j]>>bb)&1u) << j;
        row2[bb]=r;
      }
      unsigned rows[12]={}; int nr=0;
      Ech P1{}; Ech P2{}; Ech ER{};
      for(int pick=0;pick<4;++pick){
        int b1=-1;
        for(int bb=0;bb<6;++bb){ if(ech_red(P1, 1u<<bb)){ b1=bb; break; } }
        int b2=-1;
        for(int bb=0;bb<12;++bb){ if(ech_red(P2, row2[bb])){ b2=bb; break; } }
        if(b1<0||b2<0){ P.ok=false; return P; }
        unsigned p2x=row2[b1];
        unsigned p1y=(b2<6)?(1u<<b2):0u;
        unsigned f=0, p1f=0, p2f=0;
        if(ech_red(P2,p2x))      { f=1u<<b1;            p1f=1u<<b1;          p2f=p2x; }
        else if(ech_red(P1,p1y)) { f=1u<<b2;            p1f=p1y;             p2f=row2[b2]; }
        else                     { f=(1u<<b1)^(1u<<b2); p1f=(1u<<b1)^p1y;    p2f=p2x^row2[b2]; }
        unsigned v1=ech_red(P1,p1f), v2=ech_red(P2,p2f);
        if(!v1||!v2){ P.ok=false; return P; }
        ech_add(P1,v1); ech_add(P2,v2);
        unsigned vr=ech_red(ER,f);
        if(!vr){ P.ok=false; return P; }
        ech_add(ER,vr);
        rows[nr++]=f;
      }
      for(int bb=0;bb<12 && nr<12;++bb){
        unsigned vr=ech_red(ER,1u<<bb); if(!vr) continue;
        ech_add(ER,vr); rows[nr++]=1u<<bb;
      }
      if(nr!=12){ P.ok=false; return P; }
      unsigned Wcol[12]={};
      for(int j=0;j<12;++j){
        unsigned v=0;
        for(int i=0;i<12;++i) v |= ((rows[i]>>j)&1u)<<i;
        Wcol[j]=v;
      }
      for(int j=0;j<8;++j){
        P.WTC[g][j]=Wcol[j];
        unsigned v=0;
        for(int q=0;q<12;++q) if((u[j]>>q)&1u) v^=Wcol[q];
        P.RDC[g][j]=v;
      }
      for(int k=0;k<16;++k){
        unsigned wv=0, rv=0;
        for(int i=0;i<4;++i) if((k>>i)&1){
          wv ^= Wcol[8+i];
          unsigned v=0;
          for(int q=0;q<12;++q) if((rk[i]>>q)&1u) v^=Wcol[q];
          rv ^= v;
        }
        P.WK16[g][k]=wv; P.WRK16[g][k]=rv;
      }
    }
    Bprev=Bg;
  }
  for(int o=0;o<NOUT;++o){
    unsigned sr=0;
    for(int j=0;j<12;++j) sr|=(unsigned)(pcnt(Bprev.col[j]&MR[o])&1)<<j;
    P.SRlow[o]=sr&255u; P.SRhigh[o]=sr>>8;
  }
  return P;
}

constexpr Plan PLC = make_plan();        // single constexpr evaluation
static_assert(PLC.ok, "basis/bank planning failed");
__device__ constexpr Plan PL = PLC;      // constant init (copy), no re-eval

// ======================= device helpers =======================

// gw: 8 packed cpairs per gate: c00,d00,c01,d01,c10,d10,c11,d11
// where c = [ur,ur], d = [-ui,ui].
__device__ __forceinline__ void apply_group(f32x2* a, const cpair* gw, int g){
  #pragma unroll
  for(int i=0;i<4;++i){
    const cpair* w = gw + (g*4+i)*8;
    const cpair c00=w[0], d00=w[1], c01=w[2], d01=w[3];
    const cpair c10=w[4], d10=w[5], c11=w[6], d11=w[7];
    #pragma unroll
    for(int q=0;q<8;++q){
      const int k0=((q>>i)<<(i+1))|(q&((1<<i)-1));
      const int k1=k0|(1<<i);
      f32x2 a0=a[k0], a1=a[k1];
      f32x2 n0, n1;
      PK_MUL  (n0, c00, a0);
      PK_FMA_SW(n0, d00, a0);
      PK_FMA  (n0, c01, a1);
      PK_FMA_SW(n0, d01, a1);
      PK_MUL  (n1, c10, a0);
      PK_FMA_SW(n1, d10, a0);
      PK_FMA  (n1, c11, a1);
      PK_FMA_SW(n1, d11, a1);
      a[k0]=n0; a[k1]=n1;
    }
  }
}

__device__ __forceinline__ void gate_coeffs(const float* __restrict__ wts, int gi, float* o){
  const float* w = wts + gi*3;
  float st,ct;  sincosf(0.5f*w[1],&st,&ct);
  float sap,cap; sincosf(0.5f*(w[0]+w[2]),&sap,&cap);
  float sam,cam; sincosf(0.5f*(w[0]-w[2]),&sam,&cam);
  o[0]= cap*ct; o[1]=-sap*ct;   // u00
  o[2]=-cam*st; o[3]=-sam*st;   // u01
  o[4]= cam*st; o[5]=-sam*st;   // u10
  o[6]= cap*ct; o[7]= sap*ct;   // u11
}

__device__ __forceinline__ void pack_coeffs(const float* o, float* p16){
  #pragma unroll
  for(int e=0;e<4;++e){
    float ur=o[2*e], ui=o[2*e+1];
    p16[e*4+0]=ur;  p16[e*4+1]=ur;    // c = [ur,ur]
    p16[e*4+2]=-ui; p16[e*4+3]=ui;    // d = [-ui,ui]
  }
}

__global__ void coeff_kernel(const float* __restrict__ wts, float* __restrict__ gws){
  int gi = threadIdx.x;
  if(gi >= NGATE) return;
  float o[8], p16[16];
  gate_coeffs(wts, gi, o);
  pack_coeffs(o, p16);
  #pragma unroll
  for(int j=0;j<16;++j) gws[gi*16+j]=p16[j];
}

// ======================= main kernel =======================

template<bool USE_WS>
__global__ __launch_bounds__(TPB,4)
void vqc_kernel(const float* __restrict__ inp,   // (B,12)
                const float* __restrict__ wts,   // (4,12,3) fallback
                const float* __restrict__ gws,   // (48,16) packed coeffs
                float* __restrict__ out)         // (B,4)
{
  constexpr int SMEM_BYTES = DIM*8 + (USE_WS?0:NGATE*16*4);
  __shared__ __align__(16) char smem[SMEM_BYTES];
  f32x2* amp = (f32x2*)smem;
  float* cs  = (float*)smem;         // floats 0..11   (pre-amp phase)
  float* ss  = cs + NW;              // floats 12..23  (pre-amp phase)
  float* red = cs + 2*NW;            // floats 24..39  (post-amp phase)
  float* gtab = (float*)(smem + DIM*8);  // fallback only

  const int t = threadIdx.x;
  const int b = blockIdx.x;

  if(t < NW){
    float x = inp[b*NW+t];
    float s,c; sincosf(0.78539816339744830962f*x,&s,&c);
    cs[t]=c; ss[t]=s;
  }
  if(!USE_WS && t < NGATE){
    float o[8], p16[16];
    gate_coeffs(wts,t,o);
    pack_coeffs(o,p16);
    #pragma unroll
    for(int j=0;j<16;++j) gtab[t*16+j]=p16[j];
  }
  __syncthreads();

  const cpair* gw = USE_WS ? (const cpair*)gws : (const cpair*)gtab;

  float cr[NW], sr_[NW];
  #pragma unroll
  for(int w=0;w<NW;++w){ cr[w]=cs[w]; sr_[w]=ss[w]; }

  // product-state init in basis B_0
  unsigned sig_t=0;
  #pragma unroll
  for(int j=0;j<8;++j) sig_t ^= ((t>>j)&1u)? PL.SCOL0[j] : 0u;
  float pbase=1.f;
  #pragma unroll
  for(int p=0;p<12;++p)
    if(!((PL.TM>>p)&1u))
      pbase *= ((sig_t>>p)&1u)? sr_[11-p] : cr[11-p];
  f32x2 a[16];
  #pragma unroll
  for(int k=0;k<16;++k){
    float pk=pbase;
    #pragma unroll
    for(int p=0;p<12;++p)
      if((PL.TM>>p)&1u){
        unsigned bit = ((sig_t ^ PL.SK16_0[k])>>p)&1u;
        pk *= bit? sr_[11-p] : cr[11-p];
      }
    a[k].x=pk; a[k].y=0.f;
  }

  apply_group(a, gw, 0);

  #pragma unroll 1
  for(int g=1; g<12; ++g){
    unsigned wb=0, rb=0;
    #pragma unroll
    for(int j=0;j<8;++j){
      wb ^= ((t>>j)&1u)? PL.WTC[g][j] : 0u;
      rb ^= ((t>>j)&1u)? PL.RDC[g][j] : 0u;
    }
    __syncthreads();                           // prior reads done
    #pragma unroll
    for(int k=0;k<16;++k) amp[wb ^ PL.WK16[g][k]] = a[k];   // rank-4 banks
    __syncthreads();
    #pragma unroll
    for(int k=0;k<16;++k) a[k] = amp[rb ^ PL.WRK16[g][k]];  // rank-4 banks
    apply_group(a, gw, g);
  }

  // expval(PauliZ) wires 0..3 from registers
  float acc[NOUT]={0.f,0.f,0.f,0.f};
  float sg[NOUT];
  #pragma unroll
  for(int o=0;o<NOUT;++o)
    sg[o] = (__popc((unsigned)t & PL.SRlow[o])&1)? -1.f : 1.f;
  #pragma unroll
  for(int k=0;k<16;++k){
    float pr = a[k].x*a[k].x + a[k].y*a[k].y;
    #pragma unroll
    for(int o=0;o<NOUT;++o){
      const bool kp = (pcnt((unsigned)k & PL.SRhigh[o])&1)!=0;  // compile-time
      float f = sg[o]*pr;
      acc[o] += kp ? -f : f;
    }
  }
  #pragma unroll
  for(int o=0;o<NOUT;++o)
    #pragma unroll
    for(int off=32; off>0; off>>=1)
      acc[o] += __shfl_down(acc[o], off);
  __syncthreads();                 // all amp reads done before red aliases it
  const int wv=t>>6, ln=t&63;
  if(ln==0){
    #pragma unroll
    for(int o=0;o<NOUT;++o) red[wv*NOUT+o]=acc[o];
  }
  __syncthreads();
  if(t<NOUT)
    out[b*NOUT+t] = red[0*NOUT+t]+red[1*NOUT+t]+red[2*NOUT+t]+red[3*NOUT+t];
}

// ======================= launch =======================

extern "C" void kernel_launch(void* const* d_in, const int* in_sizes, int n_in,
                              void* d_out, int out_size, void* d_ws, size_t ws_size,
                              hipStream_t stream) {
  const float* inp=(const float*)d_in[0];   // (1024,12) f32
  const float* wts=(const float*)d_in[1];   // (4,12,3) f32
  float* outp=(float*)d_out;                // (1024,4) f32
  const int B = in_sizes[0]/NW;
  if(ws_size >= (size_t)(NGATE*16*sizeof(float))){
    float* gws=(float*)d_ws;
    coeff_kernel<<<1,64,0,stream>>>(wts,gws);
    vqc_kernel<true><<<B,TPB,0,stream>>>(inp,wts,gws,outp);
  } else {
    vqc_kernel<false><<<B,TPB,0,stream>>>(inp,wts,nullptr,outp);
  }
}

// Round 9
// 44.281 us; speedup vs baseline: 1.3211x; 1.2122x over previous
//
#include <hip/hip_runtime.h>
#include <hip/hip_bf16.h>

#define NW 12
#define DIM 4096
#define NL 4
#define NGATE 48
#define NOUT 4
#define TPB 256

typedef float f32x2 __attribute__((ext_vector_type(2)));
typedef float f32x4 __attribute__((ext_vector_type(4)));
typedef unsigned u32x4 __attribute__((ext_vector_type(4)));
typedef short short8 __attribute__((ext_vector_type(8)));

// ======================= shared constexpr GF(2) machinery =======================
constexpr int pcnt(unsigned x){ return __builtin_popcount(x); }
constexpr int msbp(unsigned x){ return x ? 31-__builtin_clz(x) : -1; }
constexpr unsigned ring_fwd(unsigned x,int r){
  for(int w=0;w<NW;++w){ int c=NW-1-w,t=NW-1-((w+r)%NW); x^=((x>>c)&1u)<<t; } return x;
}
constexpr unsigned ring_rev(unsigned x,int r){
  for(int w=NW-1;w>=0;--w){ int c=NW-1-w,t=NW-1-((w+r)%NW); x^=((x>>c)&1u)<<t; } return x;
}
struct Mat { unsigned col[12]; };
constexpr unsigned apply_cols(const Mat&M, unsigned v){
  unsigned r=0; for(int j=0;j<12;++j) if((v>>j)&1u) r^=M.col[j]; return r;
}
constexpr unsigned apply_rows(const unsigned* rows, unsigned v){
  unsigned r=0; for(int i=0;i<12;++i) r|=(unsigned)(pcnt(rows[i]&v)&1)<<i; return r;
}
constexpr bool invert_rows(const Mat&M, unsigned* ri_out){
  unsigned rb[12]={}, ri[12]={};
  for(int i=0;i<12;++i){ unsigned r=0; for(int j=0;j<12;++j) r|=((M.col[j]>>i)&1u)<<j; rb[i]=r; ri[i]=1u<<i; }
  for(int c=0;c<12;++c){
    int piv=-1; for(int r=c;r<12;++r) if((rb[r]>>c)&1u){piv=r;break;}
    if(piv<0) return false;
    unsigned t=rb[c]; rb[c]=rb[piv]; rb[piv]=t; t=ri[c]; ri[c]=ri[piv]; ri[piv]=t;
    for(int r=0;r<12;++r) if(r!=c&&((rb[r]>>c)&1u)){ rb[r]^=rb[c]; ri[r]^=ri[c]; }
  }
  for(int i=0;i<12;++i) ri_out[i]=ri[i];
  return true;
}
constexpr int nullspace4(const unsigned* A0, unsigned* out){
  unsigned A[4]={}; for(int i=0;i<4;++i) A[i]=A0[i];
  int rank=0; int pivc[4]={-1,-1,-1,-1};
  for(int c=0;c<12&&rank<4;++c){
    int piv=-1; for(int r=rank;r<4;++r) if((A[r]>>c)&1u){piv=r;break;}
    if(piv<0) continue;
    unsigned t=A[rank];A[rank]=A[piv];A[piv]=t;
    for(int r=0;r<4;++r) if(r!=rank&&((A[r]>>c)&1u)) A[r]^=A[rank];
    pivc[rank]=c; ++rank;
  }
  if(rank!=4) return -1;
  bool ispiv[12]={};
  for(int r=0;r<4;++r) ispiv[pivc[r]]=true;
  int cnt=0;
  for(int f=0;f<12;++f) if(!ispiv[f]){
    unsigned v=1u<<f;
    for(int r=0;r<4;++r) if((A[r]>>f)&1u) v|=1u<<pivc[r];
    out[cnt++]=v;
  }
  return cnt;
}
struct Ech { unsigned r[12]; int lead[12]; int n; };
constexpr unsigned ech_red(const Ech&e, unsigned v){
  int mv=msbp(v);
  for(int i=0;i<e.n&&v;++i) if(e.lead[i]==mv){ v^=e.r[i]; mv=msbp(v); }
  return v;
}
constexpr void ech_add(Ech&e, unsigned v){
  int l=msbp(v); int pos=e.n;
  while(pos>0&&e.lead[pos-1]<l){ e.r[pos]=e.r[pos-1]; e.lead[pos]=e.lead[pos-1]; --pos; }
  e.r[pos]=v; e.lead[pos]=l; e.n+=1;
}

// circuit masks shared by both planners
struct Circ {
  unsigned M[NL][12]; unsigned RM[NL][12]; unsigned MR[NOUT];
};
constexpr Circ make_circ(){
  Circ C{};
  unsigned cols[12]={}, icols[12]={};
  for(int p=0;p<12;++p){ cols[p]=1u<<p; icols[p]=1u<<p; }
  for(int l=0;l<NL;++l){
    for(int w=0;w<NW;++w){
      int p=NW-1-w;
      C.M[l][w]=icols[p];
      unsigned r=0; for(int j=0;j<12;++j) r|=((cols[j]>>p)&1u)<<j;
      C.RM[l][w]=r;
    }
    int rr=(l%(NW-1))+1;
    for(int j=0;j<12;++j) cols[j]=ring_fwd(cols[j],rr);
    unsigned nic[12]={};
    for(int p=0;p<12;++p){
      unsigned y=ring_rev(1u<<p,rr), v=0;
      for(int q=0;q<12;++q) if((y>>q)&1u) v^=icols[q];
      nic[p]=v;
    }
    for(int p=0;p<12;++p) icols[p]=nic[p];
  }
  for(int o=0;o<NOUT;++o){
    int p=NW-1-o; unsigned r=0;
    for(int j=0;j<12;++j) r|=((cols[j]>>p)&1u)<<j;
    C.MR[o]=r;
  }
  return C;
}

// ======================= Plan2: MFMA layout =======================
// phys y (12b): 0-3 = n (lane&15), 4-5 = T (tile slot), 6-7 = w (wave),
//               8-9 = q/rq (r-bits 0,1), 10-11 = h/s (lane>>4, r-bits 2,3).
// Gates of group g act on r-bits = y8..11 (gate i <-> y_{8+i}) — same
// algebra as the proven R6 planner. Exchange stores value at
// addr = A(Phi(y_old)), A(v) = (v>>8)*2048 + (v&255)*8; reader maps new
// coords via M = Binv_prev∘B_cur. Phi's 4 low rows are rank-4 on both the
// write-lane span {e0..3,e10,e11} and read-lane span {u0..3,rk2,rk3}
// (two-subspace avoidance) -> b64 bank floor both sides.

constexpr unsigned amap(unsigned v){ return (v>>8)*2048u + (v&255u)*8u; }

struct Plan2 {
  unsigned SCOLt[8];
  unsigned SK16[16];
  unsigned TM;
  unsigned WBC[12][8], WOFF[12][16];
  unsigned RBC[12][8], ROFF[12][16];
  unsigned SRt[NOUT], KP[NOUT];
  bool ok;
};

constexpr Plan2 make_plan2(){
  Plan2 P{}; P.ok=true;
  constexpr Circ C = make_circ();
  const int SIGl[8] = {0,1,2,3,10,11,6,7};
  Mat Bprev{}; for(int j=0;j<12;++j) Bprev.col[j]=1u<<j;
  for(int g=0; g<12; ++g){
    int l=g/3, j0=(g%3)*4;
    unsigned mi[4]={}, rmi[4]={};
    for(int i=0;i<4;++i){ mi[i]=C.M[l][j0+i]; rmi[i]=C.RM[l][j0+i]; }
    unsigned u[8]={};
    if(nullspace4(rmi,u)!=8){ P.ok=false; return P; }
    unsigned binv[12]={};
    if(!invert_rows(Bprev,binv)){ P.ok=false; return P; }
    for(int s=0;s<8;++s) u[s]=apply_rows(binv,u[s]);
    Mat Bg{};
    for(int j=0;j<8;++j) Bg.col[j]=apply_cols(Bprev,u[j]);
    for(int i=0;i<4;++i) Bg.col[8+i]=mi[i];
    unsigned tinv[12]={};
    if(!invert_rows(Bg,tinv)){ P.ok=false; return P; }
    for(int i=0;i<4;++i)
      for(int j=0;j<12;++j){
        int want=(j==8+i)?1:0;
        if((pcnt(Bg.col[j]&rmi[i])&1)!=want){ P.ok=false; return P; }
      }
    if(g==0){
      for(int j=0;j<8;++j) P.SCOLt[j]=Bg.col[SIGl[j]];
      for(int idx=0;idx<16;++idx){
        unsigned v=0;
        if((idx>>2)&1) v^=Bg.col[4];
        if((idx>>2)&2) v^=Bg.col[5];
        if(idx&1) v^=Bg.col[8];
        if(idx&2) v^=Bg.col[9];
        P.SK16[idx]=v; P.TM|=v;
      }
    } else {
      unsigned rk[4]={};
      for(int i=0;i<4;++i){
        rk[i]=apply_rows(binv,mi[i]);
        if(apply_cols(Bprev,rk[i])!=mi[i]){ P.ok=false; return P; }
      }
      unsigned s2b[6]={u[0],u[1],u[2],u[3],rk[2],rk[3]};
      unsigned rows[12]={}; int nr=0;
      Ech P1{},P2{},ER{};
      for(int pick=0;pick<4;++pick){
        unsigned fx=0, fy=0;
        const int b1s[6]={0,1,2,3,10,11};
        for(int ii=0;ii<6;++ii){
          unsigned f=1u<<b1s[ii];
          unsigned p1=(f&15u)|(((f>>10)&3u)<<4);
          if(ech_red(P1,p1)){ fx=f; break; }
        }
        for(int bb=0;bb<12;++bb){
          unsigned f=1u<<bb, p2=0;
          for(int i2=0;i2<6;++i2) p2|=(unsigned)(pcnt(f&s2b[i2])&1)<<i2;
          if(ech_red(P2,p2)){ fy=f; break; }
        }
        if(!fx||!fy){ P.ok=false; return P; }
        unsigned cand[3]={fx,fy,fx^fy};
        unsigned chosen=0, cp1=0, cp2=0;
        for(int ci=0; ci<3 && !chosen; ++ci){
          unsigned f=cand[ci];
          unsigned p1=(f&15u)|(((f>>10)&3u)<<4);
          unsigned p2=0; for(int i2=0;i2<6;++i2) p2|=(unsigned)(pcnt(f&s2b[i2])&1)<<i2;
          if(ech_red(P1,p1)&&ech_red(P2,p2)){ chosen=f; cp1=p1; cp2=p2; }
        }
        if(!chosen){ P.ok=false; return P; }
        { unsigned v1=ech_red(P1,cp1); ech_add(P1,v1); }
        { unsigned v2=ech_red(P2,cp2); ech_add(P2,v2); }
        { unsigned vr=ech_red(ER,chosen); if(!vr){ P.ok=false; return P; } ech_add(ER,vr); }
        rows[nr++]=chosen;
      }
      for(int bb=0;bb<12 && nr<12;++bb){
        unsigned vr=ech_red(ER,1u<<bb); if(!vr) continue;
        ech_add(ER,vr); rows[nr++]=1u<<bb;
      }
      if(nr!=12){ P.ok=false; return P; }
      unsigned PhiCol[12]={};
      for(int j=0;j<12;++j){
        unsigned v=0;
        for(int i=0;i<12;++i) v|=(unsigned)((rows[i]>>j)&1u)<<i;
        PhiCol[j]=v;
      }
      unsigned PhiM[12]={};
      for(int j=0;j<12;++j){
        unsigned src=(j<8)? u[j] : rk[j-8];
        unsigned v=0;
        for(int q2=0;q2<12;++q2) if((src>>q2)&1u) v^=PhiCol[q2];
        PhiM[j]=v;
      }
      for(int j=0;j<8;++j){
        P.WBC[g][j]=amap(PhiCol[SIGl[j]]);
        P.RBC[g][j]=amap(PhiM[SIGl[j]]);
      }
      for(int idx=0;idx<16;++idx){
        unsigned wv=0, rv=0;
        if((idx>>2)&1){ wv^=PhiCol[4]; rv^=PhiM[4]; }
        if((idx>>2)&2){ wv^=PhiCol[5]; rv^=PhiM[5]; }
        if(idx&1){ wv^=PhiCol[8]; rv^=PhiM[8]; }
        if(idx&2){ wv^=PhiCol[9]; rv^=PhiM[9]; }
        P.WOFF[g][idx]=amap(wv); P.ROFF[g][idx]=amap(rv);
      }
    }
    Bprev=Bg;
  }
  for(int o=0;o<NOUT;++o){
    unsigned sr=0;
    for(int j=0;j<12;++j) sr|=(unsigned)(pcnt(Bprev.col[j]&C.MR[o])&1)<<j;
    unsigned srt=0;
    const int SIGl2[8] = {0,1,2,3,10,11,6,7};
    for(int j=0;j<8;++j) srt|=((sr>>SIGl2[j])&1u)<<j;
    P.SRt[o]=srt;
    unsigned kp=0;
    for(int idx=0;idx<16;++idx){
      int T=idx>>2, q=idx&3;
      unsigned bit=(((sr>>4)&1u)&(unsigned)(T&1))^(((sr>>5)&1u)&(unsigned)((T>>1)&1))
                  ^(((sr>>8)&1u)&(unsigned)(q&1))^(((sr>>9)&1u)&(unsigned)((q>>1)&1));
      kp|=bit<<idx;
    }
    P.KP[o]=kp;
  }
  return P;
}

constexpr Plan2 PL2C = make_plan2();
static_assert(PL2C.ok, "plan2 failed");
__device__ constexpr Plan2 PL2 = PL2C;

// ======================= Plan1 (R6 fallback) =======================
struct Plan {
  unsigned SCOL0[8]; unsigned SK16_0[16];
  unsigned WTC[12][8]; unsigned WK16[12][16];
  unsigned RDC[12][8]; unsigned WRK16[12][16];
  unsigned SRlow[NOUT], SRhigh[NOUT];
  unsigned TM; bool ok;
};
constexpr Plan make_plan(){
  Plan P{}; P.ok=true;
  constexpr Circ C = make_circ();
  Mat Bprev{}; for(int j=0;j<12;++j) Bprev.col[j]=1u<<j;
  for(int g=0; g<12; ++g){
    int l=g/3, j0=(g%3)*4;
    unsigned mi[4]={}, rmi[4]={};
    for(int i=0;i<4;++i){ mi[i]=C.M[l][j0+i]; rmi[i]=C.RM[l][j0+i]; }
    unsigned u[8]={};
    if(nullspace4(rmi,u)!=8){ P.ok=false; return P; }
    unsigned binv[12]={};
    if(!invert_rows(Bprev,binv)){ P.ok=false; return P; }
    for(int s=0;s<8;++s) u[s]=apply_rows(binv,u[s]);
    Mat Bg{};
    for(int j=0;j<8;++j) Bg.col[j]=apply_cols(Bprev,u[j]);
    for(int i=0;i<4;++i) Bg.col[8+i]=mi[i];
    unsigned tinv[12]={};
    if(!invert_rows(Bg,tinv)){ P.ok=false; return P; }
    for(int i=0;i<4;++i)
      for(int j=0;j<12;++j){
        int want=(j==8+i)?1:0;
        if((pcnt(Bg.col[j]&rmi[i])&1)!=want){ P.ok=false; return P; }
      }
    if(g==0){
      for(int j=0;j<8;++j) P.SCOL0[j]=Bg.col[j];
      unsigned tm=0;
      for(int k=0;k<16;++k){
        unsigned v=0; for(int i=0;i<4;++i) if((k>>i)&1) v^=Bg.col[8+i];
        P.SK16_0[k]=v; tm|=v;
      }
      P.TM=tm;
    } else {
      unsigned rk[4]={};
      for(int i=0;i<4;++i){
        rk[i]=apply_rows(binv,mi[i]);
        if(apply_cols(Bprev,rk[i])!=mi[i]){ P.ok=false; return P; }
      }
      unsigned row2[12]={};
      for(int bb=0;bb<12;++bb){
        unsigned r=0;
        for(int j=0;j<6;++j) r |= ((u[j]>>bb)&1u) << j;
        row2[bb]=r;
      }
      unsigned rows[12]={}; int nr=0;
      Ech P1{}; Ech P2{}; Ech ER{};
      for(int pick=0;pick<4;++pick){
        int b1=-1;
        for(int bb=0;bb<6;++bb){ if(ech_red(P1, 1u<<bb)){ b1=bb; break; } }
        int b2=-1;
        for(int bb=0;bb<12;++bb){ if(ech_red(P2, row2[bb])){ b2=bb; break; } }
        if(b1<0||b2<0){ P.ok=false; return P; }
        unsigned p2x=row2[b1];
        unsigned p1y=(b2<6)?(1u<<b2):0u;
        unsigned f=0, p1f=0, p2f=0;
        if(ech_red(P2,p2x))      { f=1u<<b1;            p1f=1u<<b1;          p2f=p2x; }
        else if(ech_red(P1,p1y)) { f=1u<<b2;            p1f=p1y;             p2f=row2[b2]; }
        else                     { f=(1u<<b1)^(1u<<b2); p1f=(1u<<b1)^p1y;    p2f=p2x^row2[b2]; }
        unsigned v1=ech_red(P1,p1f), v2=ech_red(P2,p2f);
        if(!v1||!v2){ P.ok=false; return P; }
        ech_add(P1,v1); ech_add(P2,v2);
        unsigned vr=ech_red(ER,f);
        if(!vr){ P.ok=false; return P; }
        ech_add(ER,vr);
        rows[nr++]=f;
      }
      for(int bb=0;bb<12 && nr<12;++bb){
        unsigned vr=ech_red(ER,1u<<bb); if(!vr) continue;
        ech_add(ER,vr); rows[nr++]=1u<<bb;
      }
      if(nr!=12){ P.ok=false; return P; }
      unsigned Wcol[12]={};
      for(int j=0;j<12;++j){
        unsigned v=0;
        for(int i=0;i<12;++i) v |= ((rows[i]>>j)&1u)<<i;
        Wcol[j]=v;
      }
      for(int j=0;j<8;++j){
        P.WTC[g][j]=Wcol[j];
        unsigned v=0;
        for(int q=0;q<12;++q) if((u[j]>>q)&1u) v^=Wcol[q];
        P.RDC[g][j]=v;
      }
      for(int k=0;k<16;++k){
        unsigned wv=0, rv=0;
        for(int i=0;i<4;++i) if((k>>i)&1){
          wv ^= Wcol[8+i];
          unsigned v=0;
          for(int q=0;q<12;++q) if((rk[i]>>q)&1u) v^=Wcol[q];
          rv ^= v;
        }
        P.WK16[g][k]=wv; P.WRK16[g][k]=rv;
      }
    }
    Bprev=Bg;
  }
  for(int o=0;o<NOUT;++o){
    unsigned sr=0;
    for(int j=0;j<12;++j) sr|=(unsigned)(pcnt(Bprev.col[j]&C.MR[o])&1)<<j;
    P.SRlow[o]=sr&255u; P.SRhigh[o]=sr>>8;
  }
  return P;
}
constexpr Plan PLC = make_plan();
static_assert(PLC.ok, "plan1 failed");
__device__ constexpr Plan PL = PLC;

// ======================= device helpers =======================
__device__ __forceinline__ void gate_coeffs(const float* __restrict__ wts, int gi, float* o){
  const float* w = wts + gi*3;
  float st,ct;  sincosf(0.5f*w[1],&st,&ct);
  float sap,cap; sincosf(0.5f*(w[0]+w[2]),&sap,&cap);
  float sam,cam; sincosf(0.5f*(w[0]-w[2]),&sam,&cam);
  o[0]= cap*ct; o[1]=-sap*ct;
  o[2]=-cam*st; o[3]=-sam*st;
  o[4]= cam*st; o[5]=-sam*st;
  o[6]= cap*ct; o[7]= sap*ct;
}
__device__ __forceinline__ unsigned cvtpk(float a, float b){
  unsigned r; asm("v_cvt_pk_bf16_f32 %0, %1, %2" : "=v"(r) : "v"(a), "v"(b)); return r;
}
__device__ __forceinline__ void split2(float x, float& hf, float& lf){
  __hip_bfloat16 hb = __float2bfloat16(x);
  hf = __bfloat162float(hb);
  lf = x - hf;
}

// ======================= coeff kernel (U-group fragments) =======================
// gfrag layout: frag (g,f): 64 lanes x 16B. frags f: 0:A1r 1:A2r 2:A1i 3:A2i 4:A1ni 5:A2ni.
// A-side element (s,j): reg=j>>1? —— packed with the SAME cvtpk order as B-side.
__global__ void coeff2_kernel(const float* __restrict__ wts, unsigned short* __restrict__ gfrag){
  const int g = blockIdx.x;          // 12
  const int tid = threadIdx.x;       // 128
  const int m = tid & 15, rp = tid >> 4;
  const int s = rp >> 1, reg = rp & 1;
  const int r0 = 4*s + 2*reg, r1 = r0 + 1;
  const int l = g/3, j0 = (g%3)*4;
  float ur0=1.f, ui0=0.f, ur1=1.f, ui1=0.f;
  #pragma unroll
  for(int i=0;i<4;++i){
    float o[8]; gate_coeffs(wts, l*NW + j0 + i, o);
    int mb=(m>>i)&1, rb0=(r0>>i)&1, rb1=(r1>>i)&1;
    float er=o[(mb*2+rb0)*2], ei=o[(mb*2+rb0)*2+1];
    float tr=ur0*er-ui0*ei, ti=ur0*ei+ui0*er; ur0=tr; ui0=ti;
    er=o[(mb*2+rb1)*2]; ei=o[(mb*2+rb1)*2+1];
    tr=ur1*er-ui1*ei; ti=ur1*ei+ui1*er; ur1=tr; ui1=ti;
  }
  float ur0h,ur0l,ur1h,ur1l, ui0h,ui0l,ui1h,ui1l;
  split2(ur0,ur0h,ur0l); split2(ur1,ur1h,ur1l);
  split2(ui0,ui0h,ui0l); split2(ui1,ui1h,ui1l);
  unsigned Urh=cvtpk(ur0h,ur1h), Url=cvtpk(ur0l,ur1l);
  unsigned Uih=cvtpk(ui0h,ui1h), Uil=cvtpk(ui0l,ui1l);
  unsigned nUih=Uih^0x80008000u, nUil=Uil^0x80008000u;
  const int lane = s*16 + m;
  unsigned p0[6]={Urh,Url,Uih,Uil,nUih,nUil};
  unsigned p1[6]={Url,Urh,Uil,Uih,nUil,nUih};
  #pragma unroll
  for(int f=0; f<6; ++f){
    unsigned* fp = (unsigned*)((char*)gfrag + ((size_t)((g*6+f)*64 + lane))*16);
    fp[reg] = p0[f];
    fp[2+reg] = p1[f];
  }
}

// ======================= MFMA main kernel =======================
__global__ __launch_bounds__(TPB,4)
void vqc_mfma(const float* __restrict__ inp, const unsigned short* __restrict__ gfrag,
              float* __restrict__ out){
  __shared__ __align__(16) char smem[DIM*8];
  float* cs = (float*)smem; float* ss = cs+NW; float* red = cs+2*NW;
  char* ampc = smem;
  const int t = threadIdx.x, b = blockIdx.x, l = t&63;
  if(t < NW){
    float x = inp[b*NW+t];
    float s,c; sincosf(0.78539816339744830962f*x,&s,&c);
    cs[t]=c; ss[t]=s;
  }
  __syncthreads();
  float ctm[12], stm[12];
  #pragma unroll
  for(int p=0;p<12;++p){ ctm[p]=cs[11-p]; stm[p]=ss[11-p]; }
  unsigned sigb=0;
  #pragma unroll
  for(int j=0;j<8;++j) sigb ^= ((t>>j)&1u)? PL2.SCOLt[j] : 0u;
  float pbase=1.f;
  #pragma unroll
  for(int p=0;p<12;++p)
    if(!((PL2C.TM>>p)&1u))
      pbase *= ((sigb>>p)&1u)? stm[p] : ctm[p];

  f32x4 Cr[4], Ci[4];
  #pragma unroll 1
  for(int g=0; g<12; ++g){
    if(g>0){
      unsigned wbase=0;
      #pragma unroll
      for(int j=0;j<8;++j) wbase ^= ((t>>j)&1u)? PL2.WBC[g][j] : 0u;
      __syncthreads();
      #pragma unroll
      for(int idx=0; idx<16; ++idx){
        const int T=idx>>2, q=idx&3;
        *(float2*)(ampc + (wbase ^ PL2.WOFF[g][idx])) = make_float2(Cr[T][q], Ci[T][q]);
      }
      __syncthreads();
    }
    short8 AF[6];
    #pragma unroll
    for(int f=0; f<6; ++f)
      AF[f] = *(const short8*)((const char*)gfrag + ((size_t)((g*6+f)*64 + l))*16);
    unsigned rbase=0;
    if(g>0){
      #pragma unroll
      for(int j=0;j<8;++j) rbase ^= ((t>>j)&1u)? PL2.RBC[g][j] : 0u;
    }
    #pragma unroll
    for(int T=0;T<4;++T){
      float2 v0,v1,v2,v3;
      if(g==0){
        float vv[4];
        #pragma unroll
        for(int rq=0;rq<4;++rq){
          unsigned sig = sigb ^ PL2.SK16[T*4+rq];
          float pk=pbase;
          #pragma unroll
          for(int p=0;p<12;++p)
            if((PL2C.TM>>p)&1u)
              pk *= ((sig>>p)&1u)? stm[p] : ctm[p];
          vv[rq]=pk;
        }
        v0=make_float2(vv[0],0.f); v1=make_float2(vv[1],0.f);
        v2=make_float2(vv[2],0.f); v3=make_float2(vv[3],0.f);
      } else {
        v0 = *(const float2*)(ampc + (rbase ^ PL2.ROFF[g][T*4+0]));
        v1 = *(const float2*)(ampc + (rbase ^ PL2.ROFF[g][T*4+1]));
        v2 = *(const float2*)(ampc + (rbase ^ PL2.ROFF[g][T*4+2]));
        v3 = *(const float2*)(ampc + (rbase ^ PL2.ROFF[g][T*4+3]));
      }
      float h0,h1,h2,h3,e0,e1,e2,e3;
      split2(v0.x,h0,e0); split2(v1.x,h1,e1); split2(v2.x,h2,e2); split2(v3.x,h3,e3);
      u32x4 bu; bu.x=cvtpk(h0,h1); bu.y=cvtpk(h2,h3); bu.z=cvtpk(e0,e1); bu.w=cvtpk(e2,e3);
      short8 Br = __builtin_bit_cast(short8, bu);
      split2(v0.y,h0,e0); split2(v1.y,h1,e1); split2(v2.y,h2,e2); split2(v3.y,h3,e3);
      u32x4 cu; cu.x=cvtpk(h0,h1); cu.y=cvtpk(h2,h3); cu.z=cvtpk(e0,e1); cu.w=cvtpk(e2,e3);
      short8 Bi = __builtin_bit_cast(short8, cu);
      const f32x4 z = {0.f,0.f,0.f,0.f};
      f32x4 cr = __builtin_amdgcn_mfma_f32_16x16x32_bf16(AF[0], Br, z, 0,0,0);
      cr = __builtin_amdgcn_mfma_f32_16x16x32_bf16(AF[1], Br, cr, 0,0,0);
      cr = __builtin_amdgcn_mfma_f32_16x16x32_bf16(AF[4], Bi, cr, 0,0,0);
      cr = __builtin_amdgcn_mfma_f32_16x16x32_bf16(AF[5], Bi, cr, 0,0,0);
      f32x4 ci = __builtin_amdgcn_mfma_f32_16x16x32_bf16(AF[2], Br, z, 0,0,0);
      ci = __builtin_amdgcn_mfma_f32_16x16x32_bf16(AF[3], Br, ci, 0,0,0);
      ci = __builtin_amdgcn_mfma_f32_16x16x32_bf16(AF[0], Bi, ci, 0,0,0);
      ci = __builtin_amdgcn_mfma_f32_16x16x32_bf16(AF[1], Bi, ci, 0,0,0);
      Cr[T]=cr; Ci[T]=ci;
    }
  }
  float acc[NOUT]={0.f,0.f,0.f,0.f};
  float sg[NOUT];
  #pragma unroll
  for(int o=0;o<NOUT;++o)
    sg[o] = (__popc((unsigned)t & PL2.SRt[o])&1)? -1.f : 1.f;
  #pragma unroll
  for(int idx=0; idx<16; ++idx){
    const int T=idx>>2, q=idx&3;
    float pr = Cr[T][q]*Cr[T][q] + Ci[T][q]*Ci[T][q];
    #pragma unroll
    for(int o=0;o<NOUT;++o){
      const bool kp = (PL2C.KP[o]>>idx)&1;
      float f = sg[o]*pr;
      acc[o] += kp? -f : f;
    }
  }
  #pragma unroll
  for(int o=0;o<NOUT;++o)
    #pragma unroll
    for(int off=32; off>0; off>>=1)
      acc[o] += __shfl_down(acc[o], off);
  __syncthreads();
  const int wv=t>>6, ln=t&63;
  if(ln==0){
    #pragma unroll
    for(int o=0;o<NOUT;++o) red[wv*NOUT+o]=acc[o];
  }
  __syncthreads();
  if(t<NOUT)
    out[b*NOUT+t] = red[0*NOUT+t]+red[1*NOUT+t]+red[2*NOUT+t]+red[3*NOUT+t];
}

// ======================= R6 fallback kernel =======================
__global__ __launch_bounds__(TPB,4)
void vqc_fb(const float* __restrict__ inp, const float* __restrict__ wts,
            float* __restrict__ out){
  __shared__ __align__(16) char smem[DIM*8 + NGATE*8*4];
  f32x2* amp = (f32x2*)smem;
  float* cs  = (float*)smem;
  float* ss  = cs + NW;
  float* red = cs + 2*NW;
  float* gtab = (float*)(smem + DIM*8);
  const int t = threadIdx.x;
  const int b = blockIdx.x;
  if(t < NW){
    float x = inp[b*NW+t];
    float s,c; sincosf(0.78539816339744830962f*x,&s,&c);
    cs[t]=c; ss[t]=s;
  }
  if(t < NGATE){
    float o[8]; gate_coeffs(wts,t,o);
    #pragma unroll
    for(int j=0;j<8;++j) gtab[t*8+j]=o[j];
  }
  __syncthreads();
  float cr[NW], sr_[NW];
  #pragma unroll
  for(int w=0;w<NW;++w){ cr[w]=cs[w]; sr_[w]=ss[w]; }
  unsigned sig_t=0;
  #pragma unroll
  for(int j=0;j<8;++j) sig_t ^= ((t>>j)&1u)? PL.SCOL0[j] : 0u;
  float pbase=1.f;
  #pragma unroll
  for(int p=0;p<12;++p)
    if(!((PLC.TM>>p)&1u))
      pbase *= ((sig_t>>p)&1u)? sr_[11-p] : cr[11-p];
  f32x2 a[16];
  #pragma unroll
  for(int k=0;k<16;++k){
    float pk=pbase;
    #pragma unroll
    for(int p=0;p<12;++p)
      if((PLC.TM>>p)&1u){
        unsigned bit = ((sig_t ^ PL.SK16_0[k])>>p)&1u;
        pk *= bit? sr_[11-p] : cr[11-p];
      }
    a[k].x=pk; a[k].y=0.f;
  }
  const float* gw = (const float*)gtab;
  #pragma unroll 1
  for(int g=0; g<12; ++g){
    if(g>0){
      unsigned wb=0, rb=0;
      #pragma unroll
      for(int j=0;j<8;++j){
        wb ^= ((t>>j)&1u)? PL.WTC[g][j] : 0u;
        rb ^= ((t>>j)&1u)? PL.RDC[g][j] : 0u;
      }
      __syncthreads();
      #pragma unroll
      for(int k=0;k<16;++k) amp[wb ^ PL.WK16[g][k]] = a[k];
      __syncthreads();
      #pragma unroll
      for(int k=0;k<16;++k) a[k] = amp[rb ^ PL.WRK16[g][k]];
    }
    #pragma unroll
    for(int i=0;i<4;++i){
      const float* w = gw + (g*4+i)*8;
      f32x2 c00={w[0],w[0]}, d00={-w[1],w[1]};
      f32x2 c01={w[2],w[2]}, d01={-w[3],w[3]};
      f32x2 c10={w[4],w[4]}, d10={-w[5],w[5]};
      f32x2 c11={w[6],w[6]}, d11={-w[7],w[7]};
      #pragma unroll
      for(int q=0;q<8;++q){
        const int k0=((q>>i)<<(i+1))|(q&((1<<i)-1));
        const int k1=k0|(1<<i);
        f32x2 a0=a[k0], a1=a[k1];
        f32x2 a0s=a0.yx, a1s=a1.yx;
        f32x2 n0 = c00*a0 + d00*a0s + c01*a1 + d01*a1s;
        f32x2 n1 = c10*a0 + d10*a0s + c11*a1 + d11*a1s;
        a[k0]=n0; a[k1]=n1;
      }
    }
  }
  float acc[NOUT]={0.f,0.f,0.f,0.f};
  float sg[NOUT];
  #pragma unroll
  for(int o=0;o<NOUT;++o)
    sg[o] = (__popc((unsigned)t & PL.SRlow[o])&1)? -1.f : 1.f;
  #pragma unroll
  for(int k=0;k<16;++k){
    float pr = a[k].x*a[k].x + a[k].y*a[k].y;
    #pragma unroll
    for(int o=0;o<NOUT;++o){
      const bool kp = (PLC.SRhigh[o]>>0 ? ((pcnt((unsigned)k & PLC.SRhigh[o])&1)!=0) : false);
      float f = sg[o]*pr;
      acc[o] += kp ? -f : f;
    }
  }
  #pragma unroll
  for(int o=0;o<NOUT;++o)
    #pragma unroll
    for(int off=32; off>0; off>>=1)
      acc[o] += __shfl_down(acc[o], off);
  __syncthreads();
  const int wv=t>>6, ln=t&63;
  if(ln==0){
    #pragma unroll
    for(int o=0;o<NOUT;++o) red[wv*NOUT+o]=acc[o];
  }
  __syncthreads();
  if(t<NOUT)
    out[b*NOUT+t] = red[0*NOUT+t]+red[1*NOUT+t]+red[2*NOUT+t]+red[3*NOUT+t];
}

// ======================= launch =======================
extern "C" void kernel_launch(void* const* d_in, const int* in_sizes, int n_in,
                              void* d_out, int out_size, void* d_ws, size_t ws_size,
                              hipStream_t stream) {
  const float* inp=(const float*)d_in[0];   // (1024,12) f32
  const float* wts=(const float*)d_in[1];   // (4,12,3) f32
  float* outp=(float*)d_out;                // (1024,4) f32
  const int B = in_sizes[0]/NW;
  const size_t FRAG_BYTES = (size_t)12*6*64*16;   // 73728
  if(ws_size >= FRAG_BYTES){
    unsigned short* gfrag=(unsigned short*)d_ws;
    coeff2_kernel<<<12,128,0,stream>>>(wts,gfrag);
    vqc_mfma<<<B,TPB,0,stream>>>(inp,gfrag,outp);
  } else {
    vqc_fb<<<B,TPB,0,stream>>>(inp,wts,outp);
  }
}

// Round 11
// 40.778 us; speedup vs baseline: 1.4346x; 1.0859x over previous
//
#include <hip/hip_runtime.h>
#include <hip/hip_bf16.h>

#define NW 12
#define DIM 4096
#define NL 4
#define NGATE 48
#define NOUT 4
#define TPB 256

typedef float f32x2 __attribute__((ext_vector_type(2)));
typedef float f32x4 __attribute__((ext_vector_type(4)));
typedef unsigned u32x4 __attribute__((ext_vector_type(4)));
typedef short short8 __attribute__((ext_vector_type(8)));

// ======================= shared constexpr GF(2) machinery =======================
constexpr int pcnt(unsigned x){ return __builtin_popcount(x); }
constexpr int msbp(unsigned x){ return x ? 31-__builtin_clz(x) : -1; }
constexpr unsigned ring_fwd(unsigned x,int r){
  for(int w=0;w<NW;++w){ int c=NW-1-w,t=NW-1-((w+r)%NW); x^=((x>>c)&1u)<<t; } return x;
}
constexpr unsigned ring_rev(unsigned x,int r){
  for(int w=NW-1;w>=0;--w){ int c=NW-1-w,t=NW-1-((w+r)%NW); x^=((x>>c)&1u)<<t; } return x;
}
struct Mat { unsigned col[12]; };
constexpr unsigned apply_cols(const Mat&M, unsigned v){
  unsigned r=0; for(int j=0;j<12;++j) if((v>>j)&1u) r^=M.col[j]; return r;
}
constexpr unsigned apply_rows(const unsigned* rows, unsigned v){
  unsigned r=0; for(int i=0;i<12;++i) r|=(unsigned)(pcnt(rows[i]&v)&1)<<i; return r;
}
constexpr bool invert_rows(const Mat&M, unsigned* ri_out){
  unsigned rb[12]={}, ri[12]={};
  for(int i=0;i<12;++i){ unsigned r=0; for(int j=0;j<12;++j) r|=((M.col[j]>>i)&1u)<<j; rb[i]=r; ri[i]=1u<<i; }
  for(int c=0;c<12;++c){
    int piv=-1; for(int r=c;r<12;++r) if((rb[r]>>c)&1u){piv=r;break;}
    if(piv<0) return false;
    unsigned t=rb[c]; rb[c]=rb[piv]; rb[piv]=t; t=ri[c]; ri[c]=ri[piv]; ri[piv]=t;
    for(int r=0;r<12;++r) if(r!=c&&((rb[r]>>c)&1u)){ rb[r]^=rb[c]; ri[r]^=ri[c]; }
  }
  for(int i=0;i<12;++i) ri_out[i]=ri[i];
  return true;
}
constexpr int nullspace4(const unsigned* A0, unsigned* out){
  unsigned A[4]={}; for(int i=0;i<4;++i) A[i]=A0[i];
  int rank=0; int pivc[4]={-1,-1,-1,-1};
  for(int c=0;c<12&&rank<4;++c){
    int piv=-1; for(int r=rank;r<4;++r) if((A[r]>>c)&1u){piv=r;break;}
    if(piv<0) continue;
    unsigned t=A[rank];A[rank]=A[piv];A[piv]=t;
    for(int r=0;r<4;++r) if(r!=rank&&((A[r]>>c)&1u)) A[r]^=A[rank];
    pivc[rank]=c; ++rank;
  }
  if(rank!=4) return -1;
  bool ispiv[12]={};
  for(int r=0;r<4;++r) ispiv[pivc[r]]=true;
  int cnt=0;
  for(int f=0;f<12;++f) if(!ispiv[f]){
    unsigned v=1u<<f;
    for(int r=0;r<4;++r) if((A[r]>>f)&1u) v|=1u<<pivc[r];
    out[cnt++]=v;
  }
  return cnt;
}
struct Ech { unsigned r[12]; int lead[12]; int n; };
constexpr unsigned ech_red(const Ech&e, unsigned v){
  int mv=msbp(v);
  for(int i=0;i<e.n&&v;++i) if(e.lead[i]==mv){ v^=e.r[i]; mv=msbp(v); }
  return v;
}
constexpr void ech_add(Ech&e, unsigned v){
  int l=msbp(v); int pos=e.n;
  while(pos>0&&e.lead[pos-1]<l){ e.r[pos]=e.r[pos-1]; e.lead[pos]=e.lead[pos-1]; --pos; }
  e.r[pos]=v; e.lead[pos]=l; e.n+=1;
}

struct Circ {
  unsigned M[NL][12]; unsigned RM[NL][12]; unsigned MR[NOUT];
};
constexpr Circ make_circ(){
  Circ C{};
  unsigned cols[12]={}, icols[12]={};
  for(int p=0;p<12;++p){ cols[p]=1u<<p; icols[p]=1u<<p; }
  for(int l=0;l<NL;++l){
    for(int w=0;w<NW;++w){
      int p=NW-1-w;
      C.M[l][w]=icols[p];
      unsigned r=0; for(int j=0;j<12;++j) r|=((cols[j]>>p)&1u)<<j;
      C.RM[l][w]=r;
    }
    int rr=(l%(NW-1))+1;
    for(int j=0;j<12;++j) cols[j]=ring_fwd(cols[j],rr);
    unsigned nic[12]={};
    for(int p=0;p<12;++p){
      unsigned y=ring_rev(1u<<p,rr), v=0;
      for(int q=0;q<12;++q) if((y>>q)&1u) v^=icols[q];
      nic[p]=v;
    }
    for(int p=0;p<12;++p) icols[p]=nic[p];
  }
  for(int o=0;o<NOUT;++o){
    int p=NW-1-o; unsigned r=0;
    for(int j=0;j<12;++j) r|=((cols[j]>>p)&1u)<<j;
    C.MR[o]=r;
  }
  return C;
}

// ======================= Plan2: MFMA layout (R9-proven) =======================
constexpr unsigned amap(unsigned v){ return (v>>8)*2048u + (v&255u)*8u; }

struct Plan2 {
  unsigned SCOLt[8];
  unsigned SK16[16];
  unsigned TM;
  unsigned WBC[12][8], WOFF[12][16];
  unsigned RBC[12][8], ROFF[12][16];
  unsigned SRt[NOUT], KP[NOUT];
  bool ok;
};

constexpr Plan2 make_plan2(){
  Plan2 P{}; P.ok=true;
  constexpr Circ C = make_circ();
  const int SIGl[8] = {0,1,2,3,10,11,6,7};
  Mat Bprev{}; for(int j=0;j<12;++j) Bprev.col[j]=1u<<j;
  for(int g=0; g<12; ++g){
    int l=g/3, j0=(g%3)*4;
    unsigned mi[4]={}, rmi[4]={};
    for(int i=0;i<4;++i){ mi[i]=C.M[l][j0+i]; rmi[i]=C.RM[l][j0+i]; }
    unsigned u[8]={};
    if(nullspace4(rmi,u)!=8){ P.ok=false; return P; }
    unsigned binv[12]={};
    if(!invert_rows(Bprev,binv)){ P.ok=false; return P; }
    for(int s=0;s<8;++s) u[s]=apply_rows(binv,u[s]);
    Mat Bg{};
    for(int j=0;j<8;++j) Bg.col[j]=apply_cols(Bprev,u[j]);
    for(int i=0;i<4;++i) Bg.col[8+i]=mi[i];
    unsigned tinv[12]={};
    if(!invert_rows(Bg,tinv)){ P.ok=false; return P; }
    for(int i=0;i<4;++i)
      for(int j=0;j<12;++j){
        int want=(j==8+i)?1:0;
        if((pcnt(Bg.col[j]&rmi[i])&1)!=want){ P.ok=false; return P; }
      }
    if(g==0){
      for(int j=0;j<8;++j) P.SCOLt[j]=Bg.col[SIGl[j]];
      for(int idx=0;idx<16;++idx){
        unsigned v=0;
        if((idx>>2)&1) v^=Bg.col[4];
        if((idx>>2)&2) v^=Bg.col[5];
        if(idx&1) v^=Bg.col[8];
        if(idx&2) v^=Bg.col[9];
        P.SK16[idx]=v; P.TM|=v;
      }
    } else {
      unsigned rk[4]={};
      for(int i=0;i<4;++i){
        rk[i]=apply_rows(binv,mi[i]);
        if(apply_cols(Bprev,rk[i])!=mi[i]){ P.ok=false; return P; }
      }
      unsigned s2b[6]={u[0],u[1],u[2],u[3],rk[2],rk[3]};
      unsigned rows[12]={}; int nr=0;
      Ech P1{},P2{},ER{};
      for(int pick=0;pick<4;++pick){
        unsigned fx=0, fy=0;
        const int b1s[6]={0,1,2,3,10,11};
        for(int ii=0;ii<6;++ii){
          unsigned f=1u<<b1s[ii];
          unsigned p1=(f&15u)|(((f>>10)&3u)<<4);
          if(ech_red(P1,p1)){ fx=f; break; }
        }
        for(int bb=0;bb<12;++bb){
          unsigned f=1u<<bb, p2=0;
          for(int i2=0;i2<6;++i2) p2|=(unsigned)(pcnt(f&s2b[i2])&1)<<i2;
          if(ech_red(P2,p2)){ fy=f; break; }
        }
        if(!fx||!fy){ P.ok=false; return P; }
        unsigned cand[3]={fx,fy,fx^fy};
        unsigned chosen=0, cp1=0, cp2=0;
        for(int ci=0; ci<3 && !chosen; ++ci){
          unsigned f=cand[ci];
          unsigned p1=(f&15u)|(((f>>10)&3u)<<4);
          unsigned p2=0; for(int i2=0;i2<6;++i2) p2|=(unsigned)(pcnt(f&s2b[i2])&1)<<i2;
          if(ech_red(P1,p1)&&ech_red(P2,p2)){ chosen=f; cp1=p1; cp2=p2; }
        }
        if(!chosen){ P.ok=false; return P; }
        { unsigned v1=ech_red(P1,cp1); ech_add(P1,v1); }
        { unsigned v2=ech_red(P2,cp2); ech_add(P2,v2); }
        { unsigned vr=ech_red(ER,chosen); if(!vr){ P.ok=false; return P; } ech_add(ER,vr); }
        rows[nr++]=chosen;
      }
      for(int bb=0;bb<12 && nr<12;++bb){
        unsigned vr=ech_red(ER,1u<<bb); if(!vr) continue;
        ech_add(ER,vr); rows[nr++]=1u<<bb;
      }
      if(nr!=12){ P.ok=false; return P; }
      unsigned PhiCol[12]={};
      for(int j=0;j<12;++j){
        unsigned v=0;
        for(int i=0;i<12;++i) v|=(unsigned)((rows[i]>>j)&1u)<<i;
        PhiCol[j]=v;
      }
      unsigned PhiM[12]={};
      for(int j=0;j<12;++j){
        unsigned src=(j<8)? u[j] : rk[j-8];
        unsigned v=0;
        for(int q2=0;q2<12;++q2) if((src>>q2)&1u) v^=PhiCol[q2];
        PhiM[j]=v;
      }
      for(int j=0;j<8;++j){
        P.WBC[g][j]=amap(PhiCol[SIGl[j]]);
        P.RBC[g][j]=amap(PhiM[SIGl[j]]);
      }
      for(int idx=0;idx<16;++idx){
        unsigned wv=0, rv=0;
        if((idx>>2)&1){ wv^=PhiCol[4]; rv^=PhiM[4]; }
        if((idx>>2)&2){ wv^=PhiCol[5]; rv^=PhiM[5]; }
        if(idx&1){ wv^=PhiCol[8]; rv^=PhiM[8]; }
        if(idx&2){ wv^=PhiCol[9]; rv^=PhiM[9]; }
        P.WOFF[g][idx]=amap(wv); P.ROFF[g][idx]=amap(rv);
      }
    }
    Bprev=Bg;
  }
  for(int o=0;o<NOUT;++o){
    unsigned sr=0;
    for(int j=0;j<12;++j) sr|=(unsigned)(pcnt(Bprev.col[j]&C.MR[o])&1)<<j;
    unsigned srt=0;
    const int SIGl2[8] = {0,1,2,3,10,11,6,7};
    for(int j=0;j<8;++j) srt|=((sr>>SIGl2[j])&1u)<<j;
    P.SRt[o]=srt;
    unsigned kp=0;
    for(int idx=0;idx<16;++idx){
      int T=idx>>2, q=idx&3;
      unsigned bit=(((sr>>4)&1u)&(unsigned)(T&1))^(((sr>>5)&1u)&(unsigned)((T>>1)&1))
                  ^(((sr>>8)&1u)&(unsigned)(q&1))^(((sr>>9)&1u)&(unsigned)((q>>1)&1));
      kp|=bit<<idx;
    }
    P.KP[o]=kp;
  }
  return P;
}

constexpr Plan2 PL2C = make_plan2();
static_assert(PL2C.ok, "plan2 failed");
__device__ constexpr Plan2 PL2 = PL2C;

// ======================= Plan1 (R6 fallback) =======================
struct Plan {
  unsigned SCOL0[8]; unsigned SK16_0[16];
  unsigned WTC[12][8]; unsigned WK16[12][16];
  unsigned RDC[12][8]; unsigned WRK16[12][16];
  unsigned SRlow[NOUT], SRhigh[NOUT];
  unsigned TM; bool ok;
};
constexpr Plan make_plan(){
  Plan P{}; P.ok=true;
  constexpr Circ C = make_circ();
  Mat Bprev{}; for(int j=0;j<12;++j) Bprev.col[j]=1u<<j;
  for(int g=0; g<12; ++g){
    int l=g/3, j0=(g%3)*4;
    unsigned mi[4]={}, rmi[4]={};
    for(int i=0;i<4;++i){ mi[i]=C.M[l][j0+i]; rmi[i]=C.RM[l][j0+i]; }
    unsigned u[8]={};
    if(nullspace4(rmi,u)!=8){ P.ok=false; return P; }
    unsigned binv[12]={};
    if(!invert_rows(Bprev,binv)){ P.ok=false; return P; }
    for(int s=0;s<8;++s) u[s]=apply_rows(binv,u[s]);
    Mat Bg{};
    for(int j=0;j<8;++j) Bg.col[j]=apply_cols(Bprev,u[j]);
    for(int i=0;i<4;++i) Bg.col[8+i]=mi[i];
    unsigned tinv[12]={};
    if(!invert_rows(Bg,tinv)){ P.ok=false; return P; }
    for(int i=0;i<4;++i)
      for(int j=0;j<12;++j){
        int want=(j==8+i)?1:0;
        if((pcnt(Bg.col[j]&rmi[i])&1)!=want){ P.ok=false; return P; }
      }
    if(g==0){
      for(int j=0;j<8;++j) P.SCOL0[j]=Bg.col[j];
      unsigned tm=0;
      for(int k=0;k<16;++k){
        unsigned v=0; for(int i=0;i<4;++i) if((k>>i)&1) v^=Bg.col[8+i];
        P.SK16_0[k]=v; tm|=v;
      }
      P.TM=tm;
    } else {
      unsigned rk[4]={};
      for(int i=0;i<4;++i){
        rk[i]=apply_rows(binv,mi[i]);
        if(apply_cols(Bprev,rk[i])!=mi[i]){ P.ok=false; return P; }
      }
      unsigned row2[12]={};
      for(int bb=0;bb<12;++bb){
        unsigned r=0;
        for(int j=0;j<6;++j) r |= ((u[j]>>bb)&1u) << j;
        row2[bb]=r;
      }
      unsigned rows[12]={}; int nr=0;
      Ech P1{}; Ech P2{}; Ech ER{};
      for(int pick=0;pick<4;++pick){
        int b1=-1;
        for(int bb=0;bb<6;++bb){ if(ech_red(P1, 1u<<bb)){ b1=bb; break; } }
        int b2=-1;
        for(int bb=0;bb<12;++bb){ if(ech_red(P2, row2[bb])){ b2=bb; break; } }
        if(b1<0||b2<0){ P.ok=false; return P; }
        unsigned p2x=row2[b1];
        unsigned p1y=(b2<6)?(1u<<b2):0u;
        unsigned f=0, p1f=0, p2f=0;
        if(ech_red(P2,p2x))      { f=1u<<b1;            p1f=1u<<b1;          p2f=p2x; }
        else if(ech_red(P1,p1y)) { f=1u<<b2;            p1f=p1y;             p2f=row2[b2]; }
        else                     { f=(1u<<b1)^(1u<<b2); p1f=(1u<<b1)^p1y;    p2f=p2x^row2[b2]; }
        unsigned v1=ech_red(P1,p1f), v2=ech_red(P2,p2f);
        if(!v1||!v2){ P.ok=false; return P; }
        ech_add(P1,v1); ech_add(P2,v2);
        unsigned vr=ech_red(ER,f);
        if(!vr){ P.ok=false; return P; }
        ech_add(ER,vr);
        rows[nr++]=f;
      }
      for(int bb=0;bb<12 && nr<12;++bb){
        unsigned vr=ech_red(ER,1u<<bb); if(!vr) continue;
        ech_add(ER,vr); rows[nr++]=1u<<bb;
      }
      if(nr!=12){ P.ok=false; return P; }
      unsigned Wcol[12]={};
      for(int j=0;j<12;++j){
        unsigned v=0;
        for(int i=0;i<12;++i) v |= ((rows[i]>>j)&1u)<<i;
        Wcol[j]=v;
      }
      for(int j=0;j<8;++j){
        P.WTC[g][j]=Wcol[j];
        unsigned v=0;
        for(int q=0;q<12;++q) if((u[j]>>q)&1u) v^=Wcol[q];
        P.RDC[g][j]=v;
      }
      for(int k=0;k<16;++k){
        unsigned wv=0, rv=0;
        for(int i=0;i<4;++i) if((k>>i)&1){
          wv ^= Wcol[8+i];
          unsigned v=0;
          for(int q=0;q<12;++q) if((rk[i]>>q)&1u) v^=Wcol[q];
          rv ^= v;
        }
        P.WK16[g][k]=wv; P.WRK16[g][k]=rv;
      }
    }
    Bprev=Bg;
  }
  for(int o=0;o<NOUT;++o){
    unsigned sr=0;
    for(int j=0;j<12;++j) sr|=(unsigned)(pcnt(Bprev.col[j]&C.MR[o])&1)<<j;
    P.SRlow[o]=sr&255u; P.SRhigh[o]=sr>>8;
  }
  return P;
}
constexpr Plan PLC = make_plan();
static_assert(PLC.ok, "plan1 failed");
__device__ constexpr Plan PL = PLC;

// ======================= device helpers =======================
__device__ __forceinline__ void gate_coeffs(const float* __restrict__ wts, int gi, float* o){
  const float* w = wts + gi*3;
  float st,ct;  sincosf(0.5f*w[1],&st,&ct);
  float sap,cap; sincosf(0.5f*(w[0]+w[2]),&sap,&cap);
  float sam,cam; sincosf(0.5f*(w[0]-w[2]),&sam,&cam);
  o[0]= cap*ct; o[1]=-sap*ct;
  o[2]=-cam*st; o[3]=-sam*st;
  o[4]= cam*st; o[5]=-sam*st;
  o[6]= cap*ct; o[7]= sap*ct;
}
__device__ __forceinline__ unsigned cvtpk(float a, float b){
  unsigned r; asm("v_cvt_pk_bf16_f32 %0, %1, %2" : "=v"(r) : "v"(a), "v"(b)); return r;
}
__device__ __forceinline__ void split2(float x, float& hf, float& lf){
  __hip_bfloat16 hb = __float2bfloat16(x);
  hf = __bfloat162float(hb);
  lf = x - hf;
}
// hardware split: cvtpk for the hi pair, expand, residual, cvtpk for lo pair
__device__ __forceinline__ void pkhl(float x0, float x1, unsigned& hw_out, unsigned& lw_out){
  unsigned hw = cvtpk(x0, x1);
  float h0 = __uint_as_float(hw << 16);
  float h1 = __uint_as_float(hw & 0xffff0000u);
  lw_out = cvtpk(x0 - h0, x1 - h1);
  hw_out = hw;
}

// ======================= coeff kernel (U-group fragments) =======================
__global__ void coeff2_kernel(const float* __restrict__ wts, unsigned short* __restrict__ gfrag){
  const int g = blockIdx.x;          // 12
  const int tid = threadIdx.x;       // 128
  const int m = tid & 15, rp = tid >> 4;
  const int s = rp >> 1, reg = rp & 1;
  const int r0 = 4*s + 2*reg, r1 = r0 + 1;
  const int l = g/3, j0 = (g%3)*4;
  float ur0=1.f, ui0=0.f, ur1=1.f, ui1=0.f;
  #pragma unroll
  for(int i=0;i<4;++i){
    float o[8]; gate_coeffs(wts, l*NW + j0 + i, o);
    int mb=(m>>i)&1, rb0=(r0>>i)&1, rb1=(r1>>i)&1;
    float er=o[(mb*2+rb0)*2], ei=o[(mb*2+rb0)*2+1];
    float tr=ur0*er-ui0*ei, ti=ur0*ei+ui0*er; ur0=tr; ui0=ti;
    er=o[(mb*2+rb1)*2]; ei=o[(mb*2+rb1)*2+1];
    tr=ur1*er-ui1*ei; ti=ur1*ei+ui1*er; ur1=tr; ui1=ti;
  }
  float ur0h,ur0l,ur1h,ur1l, ui0h,ui0l,ui1h,ui1l;
  split2(ur0,ur0h,ur0l); split2(ur1,ur1h,ur1l);
  split2(ui0,ui0h,ui0l); split2(ui1,ui1h,ui1l);
  unsigned Urh=cvtpk(ur0h,ur1h), Url=cvtpk(ur0l,ur1l);
  unsigned Uih=cvtpk(ui0h,ui1h), Uil=cvtpk(ui0l,ui1l);
  unsigned nUih=Uih^0x80008000u, nUil=Uil^0x80008000u;
  const int lane = s*16 + m;
  unsigned p0[6]={Urh,Url,Uih,Uil,nUih,nUil};
  unsigned p1[6]={Url,Urh,Uil,Uih,nUil,nUih};
  #pragma unroll
  for(int f=0; f<6; ++f){
    unsigned* fp = (unsigned*)((char*)gfrag + ((size_t)((g*6+f)*64 + lane))*16);
    fp[reg] = p0[f];
    fp[2+reg] = p1[f];
  }
}

// ======================= MFMA main kernel =======================
#define LUT_BYTES (11*64*4)
__global__ __launch_bounds__(TPB,4)
void vqc_mfma(const float* __restrict__ inp, const unsigned short* __restrict__ gfrag,
              float* __restrict__ out){
  __shared__ __align__(16) char smem[DIM*8 + LUT_BYTES];
  float* cs = (float*)smem; float* ss = cs+NW; float* red = cs+2*NW;
  char* ampc = smem;
  unsigned* blut = (unsigned*)(smem + DIM*8);
  const int t = threadIdx.x, b = blockIdx.x, l = t&63;
  if(t < NW){
    float x = inp[b*NW+t];
    float s,c; sincosf(0.78539816339744830962f*x,&s,&c);
    cs[t]=c; ss[t]=s;
  }
  // base-LUT fill: wbase/rbase nibble tables for exchanges g=1..11
  for(int e=t; e<11*64; e+=TPB){
    int gg=(e>>6)+1, idx=e&63;
    int kind=idx>>4, nib=idx&15;
    unsigned v=0;
    #pragma unroll
    for(int j=0;j<4;++j){
      if((nib>>j)&1){
        int jj = j + ((kind&1)?4:0);
        v ^= (kind<2)? PL2.WBC[gg][jj] : PL2.RBC[gg][jj];
      }
    }
    blut[e]=v;
  }
  __syncthreads();
  float ctm[12], stm[12];
  #pragma unroll
  for(int p=0;p<12;++p){ ctm[p]=cs[11-p]; stm[p]=ss[11-p]; }
  unsigned sigb=0;
  #pragma unroll
  for(int j=0;j<8;++j) sigb ^= ((t>>j)&1u)? PL2.SCOLt[j] : 0u;
  float pbase=1.f;
  #pragma unroll
  for(int p=0;p<12;++p)
    if(!((PL2C.TM>>p)&1u))
      pbase *= ((sigb>>p)&1u)? stm[p] : ctm[p];

  short8 AF[6];
  #pragma unroll
  for(int f=0; f<6; ++f)
    AF[f] = *(const short8*)((const char*)gfrag + ((size_t)(f*64 + l))*16);

  f32x4 Cr[4], Ci[4];
  #pragma unroll 1
  for(int g=0; g<12; ++g){
    unsigned rbase=0;
    if(g>0){
      const unsigned* bl = blut + (g-1)*64;
      unsigned wbase = bl[t&15] ^ bl[16 + (t>>4)];
      rbase          = bl[32 + (t&15)] ^ bl[48 + (t>>4)];
      __syncthreads();
      #pragma unroll
      for(int idx=0; idx<16; ++idx){
        const int T=idx>>2, q=idx&3;
        *(float2*)(ampc + (wbase ^ PL2.WOFF[g][idx])) = make_float2(Cr[T][q], Ci[T][q]);
      }
      __syncthreads();
    }
    #pragma unroll
    for(int T=0;T<4;++T){
      float2 v0,v1,v2,v3;
      if(g==0){
        float vv[4];
        #pragma unroll
        for(int rq=0;rq<4;++rq){
          unsigned sig = sigb ^ PL2.SK16[T*4+rq];
          float pk=pbase;
          #pragma unroll
          for(int p=0;p<12;++p)
            if((PL2C.TM>>p)&1u)
              pk *= ((sig>>p)&1u)? stm[p] : ctm[p];
          vv[rq]=pk;
        }
        v0=make_float2(vv[0],0.f); v1=make_float2(vv[1],0.f);
        v2=make_float2(vv[2],0.f); v3=make_float2(vv[3],0.f);
      } else {
        v0 = *(const float2*)(ampc + (rbase ^ PL2.ROFF[g][T*4+0]));
        v1 = *(const float2*)(ampc + (rbase ^ PL2.ROFF[g][T*4+1]));
        v2 = *(const float2*)(ampc + (rbase ^ PL2.ROFF[g][T*4+2]));
        v3 = *(const float2*)(ampc + (rbase ^ PL2.ROFF[g][T*4+3]));
      }
      unsigned h0,l0,h1,l1;
      pkhl(v0.x, v1.x, h0, l0);
      pkhl(v2.x, v3.x, h1, l1);
      u32x4 bu; bu.x=h0; bu.y=h1; bu.z=l0; bu.w=l1;
      short8 Br = __builtin_bit_cast(short8, bu);
      pkhl(v0.y, v1.y, h0, l0);
      pkhl(v2.y, v3.y, h1, l1);
      u32x4 cu; cu.x=h0; cu.y=h1; cu.z=l0; cu.w=l1;
      short8 Bi = __builtin_bit_cast(short8, cu);
      const f32x4 z = {0.f,0.f,0.f,0.f};
      f32x4 cr = __builtin_amdgcn_mfma_f32_16x16x32_bf16(AF[0], Br, z, 0,0,0);
      cr = __builtin_amdgcn_mfma_f32_16x16x32_bf16(AF[1], Br, cr, 0,0,0);
      cr = __builtin_amdgcn_mfma_f32_16x16x32_bf16(AF[4], Bi, cr, 0,0,0);
      cr = __builtin_amdgcn_mfma_f32_16x16x32_bf16(AF[5], Bi, cr, 0,0,0);
      f32x4 ci = __builtin_amdgcn_mfma_f32_16x16x32_bf16(AF[2], Br, z, 0,0,0);
      ci = __builtin_amdgcn_mfma_f32_16x16x32_bf16(AF[3], Br, ci, 0,0,0);
      ci = __builtin_amdgcn_mfma_f32_16x16x32_bf16(AF[0], Bi, ci, 0,0,0);
      ci = __builtin_amdgcn_mfma_f32_16x16x32_bf16(AF[1], Bi, ci, 0,0,0);
      Cr[T]=cr; Ci[T]=ci;
    }
    if(g<11){
      // prefetch next group's A-fragments; latency hides under next exchange
      #pragma unroll
      for(int f=0; f<6; ++f)
        AF[f] = *(const short8*)((const char*)gfrag + ((size_t)(((g+1)*6+f)*64 + l))*16);
    }
  }
  float acc[NOUT]={0.f,0.f,0.f,0.f};
  float sg[NOUT];
  #pragma unroll
  for(int o=0;o<NOUT;++o)
    sg[o] = (__popc((unsigned)t & PL2.SRt[o])&1)? -1.f : 1.f;
  #pragma unroll
  for(int idx=0; idx<16; ++idx){
    const int T=idx>>2, q=idx&3;
    float pr = Cr[T][q]*Cr[T][q] + Ci[T][q]*Ci[T][q];
    #pragma unroll
    for(int o=0;o<NOUT;++o){
      const bool kp = (PL2C.KP[o]>>idx)&1;
      float f = sg[o]*pr;
      acc[o] += kp? -f : f;
    }
  }
  #pragma unroll
  for(int o=0;o<NOUT;++o)
    #pragma unroll
    for(int off=32; off>0; off>>=1)
      acc[o] += __shfl_down(acc[o], off);
  __syncthreads();
  const int wv=t>>6, ln=t&63;
  if(ln==0){
    #pragma unroll
    for(int o=0;o<NOUT;++o) red[wv*NOUT+o]=acc[o];
  }
  __syncthreads();
  if(t<NOUT)
    out[b*NOUT+t] = red[0*NOUT+t]+red[1*NOUT+t]+red[2*NOUT+t]+red[3*NOUT+t];
}

// ======================= R6 fallback kernel =======================
__global__ __launch_bounds__(TPB,4)
void vqc_fb(const float* __restrict__ inp, const float* __restrict__ wts,
            float* __restrict__ out){
  __shared__ __align__(16) char smem[DIM*8 + NGATE*8*4];
  f32x2* amp = (f32x2*)smem;
  float* cs  = (float*)smem;
  float* ss  = cs + NW;
  float* red = cs + 2*NW;
  float* gtab = (float*)(smem + DIM*8);
  const int t = threadIdx.x;
  const int b = blockIdx.x;
  if(t < NW){
    float x = inp[b*NW+t];
    float s,c; sincosf(0.78539816339744830962f*x,&s,&c);
    cs[t]=c; ss[t]=s;
  }
  if(t < NGATE){
    float o[8]; gate_coeffs(wts,t,o);
    #pragma unroll
    for(int j=0;j<8;++j) gtab[t*8+j]=o[j];
  }
  __syncthreads();
  float cr[NW], sr_[NW];
  #pragma unroll
  for(int w=0;w<NW;++w){ cr[w]=cs[w]; sr_[w]=ss[w]; }
  unsigned sig_t=0;
  #pragma unroll
  for(int j=0;j<8;++j) sig_t ^= ((t>>j)&1u)? PL.SCOL0[j] : 0u;
  float pbase=1.f;
  #pragma unroll
  for(int p=0;p<12;++p)
    if(!((PLC.TM>>p)&1u))
      pbase *= ((sig_t>>p)&1u)? sr_[11-p] : cr[11-p];
  f32x2 a[16];
  #pragma unroll
  for(int k=0;k<16;++k){
    float pk=pbase;
    #pragma unroll
    for(int p=0;p<12;++p)
      if((PLC.TM>>p)&1u){
        unsigned bit = ((sig_t ^ PL.SK16_0[k])>>p)&1u;
        pk *= bit? sr_[11-p] : cr[11-p];
      }
    a[k].x=pk; a[k].y=0.f;
  }
  const float* gw = (const float*)gtab;
  #pragma unroll 1
  for(int g=0; g<12; ++g){
    if(g>0){
      unsigned wb=0, rb=0;
      #pragma unroll
      for(int j=0;j<8;++j){
        wb ^= ((t>>j)&1u)? PL.WTC[g][j] : 0u;
        rb ^= ((t>>j)&1u)? PL.RDC[g][j] : 0u;
      }
      __syncthreads();
      #pragma unroll
      for(int k=0;k<16;++k) amp[wb ^ PL.WK16[g][k]] = a[k];
      __syncthreads();
      #pragma unroll
      for(int k=0;k<16;++k) a[k] = amp[rb ^ PL.WRK16[g][k]];
    }
    #pragma unroll
    for(int i=0;i<4;++i){
      const float* w = gw + (g*4+i)*8;
      f32x2 c00={w[0],w[0]}, d00={-w[1],w[1]};
      f32x2 c01={w[2],w[2]}, d01={-w[3],w[3]};
      f32x2 c10={w[4],w[4]}, d10={-w[5],w[5]};
      f32x2 c11={w[6],w[6]}, d11={-w[7],w[7]};
      #pragma unroll
      for(int q=0;q<8;++q){
        const int k0=((q>>i)<<(i+1))|(q&((1<<i)-1));
        const int k1=k0|(1<<i);
        f32x2 a0=a[k0], a1=a[k1];
        f32x2 a0s=a0.yx, a1s=a1.yx;
        f32x2 n0 = c00*a0 + d00*a0s + c01*a1 + d01*a1s;
        f32x2 n1 = c10*a0 + d10*a0s + c11*a1 + d11*a1s;
        a[k0]=n0; a[k1]=n1;
      }
    }
  }
  float acc[NOUT]={0.f,0.f,0.f,0.f};
  float sg[NOUT];
  #pragma unroll
  for(int o=0;o<NOUT;++o)
    sg[o] = (__popc((unsigned)t & PL.SRlow[o])&1)? -1.f : 1.f;
  #pragma unroll
  for(int k=0;k<16;++k){
    float pr = a[k].x*a[k].x + a[k].y*a[k].y;
    #pragma unroll
    for(int o=0;o<NOUT;++o){
      const bool kp = (pcnt((unsigned)k & PLC.SRhigh[o])&1)!=0;
      float f = sg[o]*pr;
      acc[o] += kp ? -f : f;
    }
  }
  #pragma unroll
  for(int o=0;o<NOUT;++o)
    #pragma unroll
    for(int off=32; off>0; off>>=1)
      acc[o] += __shfl_down(acc[o], off);
  __syncthreads();
  const int wv=t>>6, ln=t&63;
  if(ln==0){
    #pragma unroll
    for(int o=0;o<NOUT;++o) red[wv*NOUT+o]=acc[o];
  }
  __syncthreads();
  if(t<NOUT)
    out[b*NOUT+t] = red[0*NOUT+t]+red[1*NOUT+t]+red[2*NOUT+t]+red[3*NOUT+t];
}

// ======================= launch =======================
extern "C" void kernel_launch(void* const* d_in, const int* in_sizes, int n_in,
                              void* d_out, int out_size, void* d_ws, size_t ws_size,
                              hipStream_t stream) {
  const float* inp=(const float*)d_in[0];   // (1024,12) f32
  const float* wts=(const float*)d_in[1];   // (4,12,3) f32
  float* outp=(float*)d_out;                // (1024,4) f32
  const int B = in_sizes[0]/NW;
  const size_t FRAG_BYTES = (size_t)12*6*64*16;   // 73728
  if(ws_size >= FRAG_BYTES){
    unsigned short* gfrag=(unsigned short*)d_ws;
    coeff2_kernel<<<12,128,0,stream>>>(wts,gfrag);
    vqc_mfma<<<B,TPB,0,stream>>>(inp,gfrag,outp);
  } else {
    vqc_fb<<<B,TPB,0,stream>>>(inp,wts,outp);
  }
}